// Round 7
// baseline (4234.795 us; speedup 1.0000x reference)
//
#include <hip/hip_runtime.h>
#include <stdint.h>

#define T_STEPS 300
#define T4 75

typedef __attribute__((ext_vector_type(8))) short bf16x8;
typedef __attribute__((ext_vector_type(4))) float f32x4;

// Diagnostic round: every kernel takes a runtime `reps` and repeats its full
// body. Outputs are NOT __restrict__ so stores may alias inputs -> compiler
// must re-execute loads every rep (no cross-rep CSE). reps=8 makes any
// kernel with true cost >24us exceed the 190us harness fills and surface in
// the rocprof top-5 with an 8x duration.

// ---- scan (psp + spike) constants: d = exp(-1), c = e, cr = -2*theta*e ----
__device__ __forceinline__ void scan_step(float x, float& pp, float& pq,
                                          float& rp, float& rq, float& s_out) {
    const float D  = 0.36787944117144233f;
    const float C  = 2.7182818284590452f;
    const float CR = -54.365636569180904f;
    const float TH = 10.0f;
    pq = D * (pq + pp);
    pp = D * pp + x;
    float u = C * pq;
    rq = D * (rq + rp);
    float s = (u + CR * rq >= TH) ? 1.0f : 0.0f;
    rp = D * rp + s;
    s_out = s;
}

#define SCAN4(v, PACK)                                                     \
    {                                                                      \
        float s0, s1, s2, s3;                                              \
        scan_step(v.x, pp, pq, rp, rq, s0);                                \
        scan_step(v.y, pp, pq, rp, rq, s1);                                \
        scan_step(v.z, pp, pq, rp, rq, s2);                                \
        scan_step(v.w, pp, pq, rp, rq, s3);                                \
        PACK = (uint32_t)s0 | ((uint32_t)s1 << 8) |                        \
               ((uint32_t)s2 << 16) | ((uint32_t)s3 << 24);                \
    }

#define FMA4(A, wc) A.x = fmaf(wc, f0, A.x); A.y = fmaf(wc, f1, A.y); \
                    A.z = fmaf(wc, f2, A.z); A.w = fmaf(wc, f3, A.w);

// ---- SP0 spatial: 4x4 sum-pool * 11 on raw input (t-major z out) ----
__global__ __launch_bounds__(256) void k_pool4(const float* __restrict__ in,
                                               float* z, int reps) {
    int idx = blockIdx.x * 256 + threadIdx.x;
    int t4 = idx % T4;
    int n  = idx / T4;
    int x = n & 31, y = (n >> 5) & 31, bc = n >> 10;
    const float* base = in + ((size_t)bc * 16384 + (size_t)(4 * y) * 128 + 4 * x) * T_STEPS + 4 * t4;
    for (int rep = 0; rep < reps; ++rep) {
        float4 acc = {0.f, 0.f, 0.f, 0.f};
#pragma unroll
        for (int i = 0; i < 4; ++i)
#pragma unroll
            for (int j = 0; j < 4; ++j) {
                float4 v = *reinterpret_cast<const float4*>(base + ((size_t)i * 128 + j) * T_STEPS);
                acc.x += v.x; acc.y += v.y; acc.z += v.z; acc.w += v.w;
            }
        float4 o = {11.f * acc.x, 11.f * acc.y, 11.f * acc.z, 11.f * acc.w};
        *reinterpret_cast<float4*>(z + (size_t)n * T_STEPS + 4 * t4) = o;
    }
}

// ---- scan: t-major f32 z in -> u32 spike planes out ----
__global__ __launch_bounds__(256) void k_scan_l0(const float* __restrict__ z,
                                                 uint32_t* sp, int N, int reps) {
    int n = blockIdx.x * 256 + threadIdx.x;
    if (n >= N) return;
    const float4* zp = reinterpret_cast<const float4*>(z + (size_t)n * T_STEPS);
    for (int rep = 0; rep < reps; ++rep) {
        float pp = 0.f, pq = 0.f, rp = 0.f, rq = 0.f;
#pragma unroll 2
        for (int t4 = 0; t4 < T4; ++t4) {
            float4 v = zp[t4];
            uint32_t pack;
            SCAN4(v, pack);
            sp[(size_t)t4 * N + n] = pack;
        }
    }
}

// ---- scan: f4 z planes in -> u32 spike planes out ----
__global__ __launch_bounds__(256) void k_scan_plane(const float4* __restrict__ z,
                                                    uint32_t* sp, int N, int reps) {
    int n = blockIdx.x * 256 + threadIdx.x;
    if (n >= N) return;
    for (int rep = 0; rep < reps; ++rep) {
        float pp = 0.f, pq = 0.f, rp = 0.f, rq = 0.f;
#pragma unroll 2
        for (int t4 = 0; t4 < T4; ++t4) {
            float4 v = z[(size_t)t4 * N + n];
            uint32_t pack;
            SCAN4(v, pack);
            sp[(size_t)t4 * N + n] = pack;
        }
    }
}

// ---- scan: t-major f32 z in -> t-major f32 spikes out (FC tail) ----
__global__ __launch_bounds__(256) void k_scan_f32(const float* __restrict__ z,
                                                  float* s, int N, int ostride, int reps) {
    int n = blockIdx.x * blockDim.x + threadIdx.x;
    if (n >= N) return;
    const float4* zp = reinterpret_cast<const float4*>(z + (size_t)n * T_STEPS);
    float* spo = s + (size_t)n * ostride;
    for (int rep = 0; rep < reps; ++rep) {
        float pp = 0.f, pq = 0.f, rp = 0.f, rq = 0.f;
        for (int it = 0; it < T4; ++it) {
            float4 v = zp[it];
            float4 o;
            scan_step(v.x, pp, pq, rp, rq, o.x);
            scan_step(v.y, pp, pq, rp, rq, o.y);
            scan_step(v.z, pp, pq, rp, rq, o.z);
            scan_step(v.w, pp, pq, rp, rq, o.w);
            *reinterpret_cast<float4*>(spo + it * 4) = o;
        }
    }
}

// ---- fused 2x2 sum-pool * 11 + scan on u32 spike planes (SP1) ----
template<int HW, int NIN, int NOUT>
__global__ __launch_bounds__(256) void k_pool2s(const uint32_t* __restrict__ sin,
                                                uint32_t* sout, int reps) {
    int n = blockIdx.x * 256 + threadIdx.x;
    if (n >= NOUT) return;
    int x = n % HW, y = (n / HW) % HW, bc = n / (HW * HW);
    const int W2d = HW * 2;
    const uint32_t* base0 = sin + (size_t)bc * W2d * W2d + (size_t)(2 * y) * W2d + 2 * x;
    for (int rep = 0; rep < reps; ++rep) {
        float pp = 0.f, pq = 0.f, rp = 0.f, rq = 0.f;
#pragma unroll 2
        for (int t4 = 0; t4 < T4; ++t4) {
            const uint32_t* p = base0 + (size_t)t4 * NIN;
            uint32_t sum = p[0] + p[1] + p[W2d] + p[W2d + 1];
            float4 v;
            v.x = 11.f * (float)(sum & 0xffu);
            v.y = 11.f * (float)((sum >> 8) & 0xffu);
            v.z = 11.f * (float)((sum >> 16) & 0xffu);
            v.w = 11.f * (float)(sum >> 24);
            uint32_t pack;
            SCAN4(v, pack);
            sout[(size_t)t4 * NOUT + n] = pack;
        }
    }
}

// ---- SP2: fused 2x2 pool + scan -> k-major bf16 spikes [b][320][2048] ----
__global__ __launch_bounds__(256) void k_pool2s_bf(const uint32_t* __restrict__ sin,
                                                   ushort* sb, int reps) {
    int n = blockIdx.x * 256 + threadIdx.x;
    if (n >= 16384) return;
    int x = n & 7, y = (n >> 3) & 7, bc = n >> 6;
    const uint32_t* base0 = sin + (size_t)bc * 256 + (size_t)(2 * y) * 16 + 2 * x;
    int b = n >> 11, k = n & 2047;
    ushort* out = sb + (size_t)b * 320 * 2048 + k;
    for (int rep = 0; rep < reps; ++rep) {
        float pp = 0.f, pq = 0.f, rp = 0.f, rq = 0.f;
        for (int t4 = 0; t4 < T4; ++t4) {
            const uint32_t* p = base0 + (size_t)t4 * 65536;
            uint32_t sum = p[0] + p[1] + p[16] + p[17];
            float4 v;
            v.x = 11.f * (float)(sum & 0xffu);
            v.y = 11.f * (float)((sum >> 8) & 0xffu);
            v.z = 11.f * (float)((sum >> 16) & 0xffu);
            v.w = 11.f * (float)(sum >> 24);
            float s0, s1, s2, s3;
            scan_step(v.x, pp, pq, rp, rq, s0);
            scan_step(v.y, pp, pq, rp, rq, s1);
            scan_step(v.z, pp, pq, rp, rq, s2);
            scan_step(v.w, pp, pq, rp, rq, s3);
            out[(size_t)(t4 * 4 + 0) * 2048] = s0 != 0.f ? 0x3F80 : 0;
            out[(size_t)(t4 * 4 + 1) * 2048] = s1 != 0.f ? 0x3F80 : 0;
            out[(size_t)(t4 * 4 + 2) * 2048] = s2 != 0.f ? 0x3F80 : 0;
            out[(size_t)(t4 * 4 + 3) * 2048] = s3 != 0.f ? 0x3F80 : 0;
        }
    }
}

// ---- SC1: 5x5 conv 2->16 over 32x32 ----
__global__ __launch_bounds__(256) void k_conv1(const uint32_t* __restrict__ s0p,
                                               const float* __restrict__ W1,
                                               float4* z1p, int reps) {
    __shared__ float w_lds[2][25][16];
    int bid = blockIdx.x;
    int pixblk = bid & 3;
    int t4 = (bid >> 2) % 75;
    int b  = bid / 300;
    int tid = threadIdx.x;
    for (int j = tid; j < 800; j += 256) {
        int o = j & 15, kk = (j >> 4) % 25, c = j / 400;
        w_lds[c][kk][o] = W1[(o * 2 + c) * 25 + kk];
    }
    __syncthreads();
    int pix = pixblk * 256 + tid;
    int px = pix & 31, py = pix >> 5;
    const uint32_t* pb = s0p + (size_t)t4 * 16384 + (size_t)(b * 2) * 1024;
    for (int rep = 0; rep < reps; ++rep) {
        float4 acc[16];
#pragma unroll
        for (int o = 0; o < 16; ++o) acc[o] = make_float4(0.f, 0.f, 0.f, 0.f);
        for (int c = 0; c < 2; ++c) {
#pragma unroll
            for (int ky = 0; ky < 5; ++ky) {
                int yy = py + ky - 2;
                bool rok = (unsigned)yy < 32u;
#pragma unroll
                for (int kx = 0; kx < 5; ++kx) {
                    int xx = px + kx - 2;
                    uint32_t v = 0;
                    if (rok && (unsigned)xx < 32u) v = pb[c * 1024 + yy * 32 + xx];
                    float f0 = (float)(v & 0xffu), f1 = (float)((v >> 8) & 0xffu);
                    float f2 = (float)((v >> 16) & 0xffu), f3 = (float)(v >> 24);
                    int kk = ky * 5 + kx;
#pragma unroll
                    for (int oo = 0; oo < 4; ++oo) {
                        float4 w4 = *reinterpret_cast<const float4*>(&w_lds[c][kk][oo * 4]);
                        FMA4(acc[oo * 4 + 0], w4.x);
                        FMA4(acc[oo * 4 + 1], w4.y);
                        FMA4(acc[oo * 4 + 2], w4.z);
                        FMA4(acc[oo * 4 + 3], w4.w);
                    }
                }
            }
        }
        size_t zb = (size_t)t4 * 131072 + (size_t)(b * 16) * 1024 + pix;
#pragma unroll
        for (int o = 0; o < 16; ++o) z1p[zb + o * 1024] = acc[o];
    }
}

// ---- SC2: 3x3 conv 16->32 over 16x16 ----
__global__ __launch_bounds__(256) void k_conv2(const uint32_t* __restrict__ s2p,
                                               const float* __restrict__ W2,
                                               float4* z2p, int reps) {
    __shared__ float w_lds[16][9][16];
    int bid = blockIdx.x;
    int oh = bid & 1;
    int t4 = (bid >> 1) % 75;
    int b  = bid / 150;
    int tid = threadIdx.x;
    for (int j = tid; j < 2304; j += 256) {
        int o = j & 15;
        int t9 = (j >> 4) % 9;
        int c  = j / 144;
        w_lds[c][t9][o] = W2[(size_t)((oh * 16 + o) * 16 + c) * 9 + t9];
    }
    __syncthreads();
    int px = tid & 15, py = tid >> 4;
    const uint32_t* pb = s2p + (size_t)t4 * 32768 + (size_t)(b * 16) * 256;
    for (int rep = 0; rep < reps; ++rep) {
        float4 acc[16];
#pragma unroll
        for (int o = 0; o < 16; ++o) acc[o] = make_float4(0.f, 0.f, 0.f, 0.f);
        for (int c = 0; c < 16; ++c) {
#pragma unroll
            for (int ky = 0; ky < 3; ++ky) {
                int yy = py + ky - 1;
                bool rok = (unsigned)yy < 16u;
#pragma unroll
                for (int kx = 0; kx < 3; ++kx) {
                    int xx = px + kx - 1;
                    uint32_t v = 0;
                    if (rok && (unsigned)xx < 16u) v = pb[c * 256 + yy * 16 + xx];
                    float f0 = (float)(v & 0xffu), f1 = (float)((v >> 8) & 0xffu);
                    float f2 = (float)((v >> 16) & 0xffu), f3 = (float)(v >> 24);
                    int t9 = ky * 3 + kx;
#pragma unroll
                    for (int oo = 0; oo < 4; ++oo) {
                        float4 w4 = *reinterpret_cast<const float4*>(&w_lds[c][t9][oo * 4]);
                        FMA4(acc[oo * 4 + 0], w4.x);
                        FMA4(acc[oo * 4 + 1], w4.y);
                        FMA4(acc[oo * 4 + 2], w4.z);
                        FMA4(acc[oo * 4 + 3], w4.w);
                    }
                }
            }
        }
        size_t zb = (size_t)t4 * 65536 + (size_t)(b * 32 + oh * 16) * 256 + tid;
#pragma unroll
        for (int o = 0; o < 16; ++o) z2p[zb + o * 256] = acc[o];
    }
}

// ---- Wf1 3-way bf16 split ----
__device__ __forceinline__ ushort f2bf(float f) {
    uint32_t u = __float_as_uint(f);
    u = u + 0x7fffu + ((u >> 16) & 1u);
    return (ushort)(u >> 16);
}
__device__ __forceinline__ float bf2f(ushort h) {
    return __uint_as_float((uint32_t)h << 16);
}
__global__ __launch_bounds__(256) void k_wsplit(const float* __restrict__ W,
                                                ushort* __restrict__ Wh,
                                                ushort* __restrict__ Wm,
                                                ushort* __restrict__ Wl, int n) {
    int i = blockIdx.x * 256 + threadIdx.x;
    if (i >= n) return;
    float w = W[i];
    ushort h = f2bf(w);
    float r1 = w - bf2f(h);
    ushort m = f2bf(r1);
    float r2 = r1 - bf2f(m);
    ushort l = f2bf(r2);
    Wh[i] = h; Wm[i] = m; Wl[i] = l;
}

// ---- SF1 via bf16 MFMA ----
__device__ __forceinline__ bf16x8 ldb(const ushort* p) {
    return *reinterpret_cast<const bf16x8*>(p);
}
__global__ __launch_bounds__(256) void k_fc1_mfma(const ushort* __restrict__ Wh,
                                                  const ushort* __restrict__ Wm,
                                                  const ushort* __restrict__ Wl,
                                                  const ushort* __restrict__ sb,
                                                  float* z, int reps) {
    int bid = blockIdx.x;
    int obk = bid & 7;
    int r   = bid >> 3;
    int tbk = r % 10;
    int b   = r / 10;
    int tid = threadIdx.x, lane = tid & 63, wv = tid >> 6;
    int l15 = lane & 15, l4 = lane >> 4;
    int oA = obk * 64 + (wv & 1) * 32 + l15;
    int t  = tbk * 32 + (wv >> 1) * 16 + l15;
    size_t a0 = (size_t)oA * 2048 + l4 * 8;
    size_t a1 = a0 + 16 * 2048;
    size_t bo = ((size_t)b * 320 + t) * 2048 + l4 * 8;

    for (int rep = 0; rep < reps; ++rep) {
        f32x4 acc0 = {0.f, 0.f, 0.f, 0.f};
        f32x4 acc1 = {0.f, 0.f, 0.f, 0.f};

        bf16x8 h0 = ldb(Wh + a0), h1 = ldb(Wh + a1);
        bf16x8 m0 = ldb(Wm + a0), m1 = ldb(Wm + a1);
        bf16x8 l0 = ldb(Wl + a0), l1 = ldb(Wl + a1);
        bf16x8 bb = ldb(sb + bo);

        for (int ks = 0; ks < 64; ++ks) {
            int kn = (ks < 63) ? (ks + 1) * 32 : 0;
            bf16x8 nh0 = ldb(Wh + a0 + kn), nh1 = ldb(Wh + a1 + kn);
            bf16x8 nm0 = ldb(Wm + a0 + kn), nm1 = ldb(Wm + a1 + kn);
            bf16x8 nl0 = ldb(Wl + a0 + kn), nl1 = ldb(Wl + a1 + kn);
            bf16x8 nbb = ldb(sb + bo + kn);
            acc0 = __builtin_amdgcn_mfma_f32_16x16x32_bf16(h0, bb, acc0, 0, 0, 0);
            acc1 = __builtin_amdgcn_mfma_f32_16x16x32_bf16(h1, bb, acc1, 0, 0, 0);
            acc0 = __builtin_amdgcn_mfma_f32_16x16x32_bf16(m0, bb, acc0, 0, 0, 0);
            acc1 = __builtin_amdgcn_mfma_f32_16x16x32_bf16(m1, bb, acc1, 0, 0, 0);
            acc0 = __builtin_amdgcn_mfma_f32_16x16x32_bf16(l0, bb, acc0, 0, 0, 0);
            acc1 = __builtin_amdgcn_mfma_f32_16x16x32_bf16(l1, bb, acc1, 0, 0, 0);
            h0 = nh0; h1 = nh1; m0 = nm0; m1 = nm1; l0 = nl0; l1 = nl1; bb = nbb;
        }

        if (t < T_STEPS) {
            int orow = obk * 64 + (wv & 1) * 32 + l4 * 4;
            float* zr = z + ((size_t)b * 512 + orow) * T_STEPS + t;
            zr[0 * T_STEPS] = acc0.x;  zr[1 * T_STEPS] = acc0.y;
            zr[2 * T_STEPS] = acc0.z;  zr[3 * T_STEPS] = acc0.w;
            float* zr2 = zr + 16 * T_STEPS;
            zr2[0 * T_STEPS] = acc1.x; zr2[1 * T_STEPS] = acc1.y;
            zr2[2 * T_STEPS] = acc1.z; zr2[3 * T_STEPS] = acc1.w;
        }
    }
}

// ---- SF2: 512 -> 11 FC ----
__global__ __launch_bounds__(256) void k_fc2(const float* __restrict__ s5,
                                             const float* __restrict__ Wf2,
                                             float* z, int reps) {
    int idx = blockIdx.x * 256 + threadIdx.x;
    if (idx >= 6600) return;
    int t4 = idx % T4;
    int r  = idx / T4;
    int b = r & 7, o = r >> 3;
    const float* sp = s5 + (size_t)b * 512 * T_STEPS + 4 * t4;
    const float* wp = Wf2 + (size_t)o * 512;
    for (int rep = 0; rep < reps; ++rep) {
        float a0 = 0.f, a1 = 0.f, a2 = 0.f, a3 = 0.f;
#pragma unroll 2
        for (int k = 0; k < 512; k += 4) {
            float4 wv = *reinterpret_cast<const float4*>(wp + k);
            float4 v0 = *reinterpret_cast<const float4*>(sp + (size_t)(k + 0) * T_STEPS);
            float4 v1 = *reinterpret_cast<const float4*>(sp + (size_t)(k + 1) * T_STEPS);
            float4 v2 = *reinterpret_cast<const float4*>(sp + (size_t)(k + 2) * T_STEPS);
            float4 v3 = *reinterpret_cast<const float4*>(sp + (size_t)(k + 3) * T_STEPS);
            a0 = fmaf(wv.x, v0.x, a0); a1 = fmaf(wv.x, v0.y, a1); a2 = fmaf(wv.x, v0.z, a2); a3 = fmaf(wv.x, v0.w, a3);
            a0 = fmaf(wv.y, v1.x, a0); a1 = fmaf(wv.y, v1.y, a1); a2 = fmaf(wv.y, v1.z, a2); a3 = fmaf(wv.y, v1.w, a3);
            a0 = fmaf(wv.z, v2.x, a0); a1 = fmaf(wv.z, v2.y, a1); a2 = fmaf(wv.z, v2.z, a2); a3 = fmaf(wv.z, v2.w, a3);
            a0 = fmaf(wv.w, v3.x, a0); a1 = fmaf(wv.w, v3.y, a1); a2 = fmaf(wv.w, v3.z, a2); a3 = fmaf(wv.w, v3.w, a3);
        }
        *reinterpret_cast<float4*>(z + (size_t)(b * 11 + o) * T_STEPS + 4 * t4) = make_float4(a0, a1, a2, a3);
    }
}

__global__ void k_zero(float* out, int n) {
    int i = blockIdx.x * 256 + threadIdx.x;
    if (i < n) out[i] = 0.f;
}

extern "C" void kernel_launch(void* const* d_in, const int* in_sizes, int n_in,
                              void* d_out, int out_size, void* d_ws, size_t ws_size,
                              hipStream_t stream) {
    const float* s_in = (const float*)d_in[0];
    const float* W1   = (const float*)d_in[1];
    const float* W2   = (const float*)d_in[2];
    const float* Wf1  = (const float*)d_in[3];
    const float* Wf2  = (const float*)d_in[4];
    float* out = (float*)d_out;

    const size_t OFF_Z  = 0;
    const size_t OFF_S0 = 157286400;
    const size_t OFF_S1 = 162201600;
    const size_t OFF_S2 = 201523200;
    const size_t OFF_S3 = 211353600;
    const size_t OFF_SB = 231014400;
    const size_t OFF_S5 = 241500160;
    const size_t OFF_WH = 246415360;
    const size_t OFF_WM = 248512512;
    const size_t OFF_WL = 250609664;
    const size_t NEEDED = 252706816;

    if (ws_size < NEEDED) {
        k_zero<<<(26400 + 255) / 256, 256, 0, stream>>>(out, 26400);
        return;
    }

    char* ws = (char*)d_ws;
    float*    Z   = (float*)(ws + OFF_Z);
    uint32_t* s0p = (uint32_t*)(ws + OFF_S0);
    uint32_t* s1p = (uint32_t*)(ws + OFF_S1);
    uint32_t* s2p = (uint32_t*)(ws + OFF_S2);
    uint32_t* s3p = (uint32_t*)(ws + OFF_S3);
    ushort*   sbf = (ushort*)(ws + OFF_SB);
    float*    s5  = (float*)(ws + OFF_S5);
    ushort*   Wh  = (ushort*)(ws + OFF_WH);
    ushort*   Wm  = (ushort*)(ws + OFF_WM);
    ushort*   Wl  = (ushort*)(ws + OFF_WL);

    const int R = 8;   // diagnostic repeat factor

    k_wsplit<<<4096, 256, 0, stream>>>(Wf1, Wh, Wm, Wl, 512 * 2048);

    k_pool4<<<4800, 256, 0, stream>>>(s_in, Z, R);
    k_scan_l0<<<64, 256, 0, stream>>>(Z, s0p, 16384, R);

    k_conv1<<<2400, 256, 0, stream>>>(s0p, W1, (float4*)Z, R);
    k_scan_plane<<<512, 256, 0, stream>>>((const float4*)Z, s1p, 131072, R);

    k_pool2s<16, 131072, 32768><<<128, 256, 0, stream>>>(s1p, s2p, R);

    k_conv2<<<1200, 256, 0, stream>>>(s2p, W2, (float4*)Z, R);
    k_scan_plane<<<256, 256, 0, stream>>>((const float4*)Z, s3p, 65536, R);

    k_pool2s_bf<<<64, 256, 0, stream>>>(s3p, sbf, R);

    k_fc1_mfma<<<640, 256, 0, stream>>>(Wh, Wm, Wl, sbf, Z, R);
    k_scan_f32<<<16, 256, 0, stream>>>(Z, s5, 4096, 300, R);

    k_fc2<<<26, 256, 0, stream>>>(s5, Wf2, Z, R);
    k_scan_f32<<<1, 128, 0, stream>>>(Z, out, 88, 300, R);
}

// Round 8
// 998.364 us; speedup vs baseline: 4.2417x; 4.2417x over previous
//
#include <hip/hip_runtime.h>
#include <stdint.h>

#define T_STEPS 300
#define T4 75

typedef __attribute__((ext_vector_type(8))) short bf16x8;
typedef __attribute__((ext_vector_type(4))) float f32x4;

// ---- scan (psp + spike) constants: d = exp(-1), c = e, cr = -2*theta*e ----
__device__ __forceinline__ void scan_step(float x, float& pp, float& pq,
                                          float& rp, float& rq, float& s_out) {
    const float D  = 0.36787944117144233f;
    const float C  = 2.7182818284590452f;
    const float CR = -54.365636569180904f;
    const float TH = 10.0f;
    pq = D * (pq + pp);      // psp state (q uses old p)
    pp = D * pp + x;
    float u = C * pq;
    rq = D * (rq + rp);      // refractory state
    float s = (u + CR * rq >= TH) ? 1.0f : 0.0f;
    rp = D * rp + s;
    s_out = s;
}

#define SCAN4(v, PACK)                                                     \
    {                                                                      \
        float s0, s1, s2, s3;                                              \
        scan_step(v.x, pp, pq, rp, rq, s0);                                \
        scan_step(v.y, pp, pq, rp, rq, s1);                                \
        scan_step(v.z, pp, pq, rp, rq, s2);                                \
        scan_step(v.w, pp, pq, rp, rq, s3);                                \
        PACK = (uint32_t)s0 | ((uint32_t)s1 << 8) |                        \
               ((uint32_t)s2 << 16) | ((uint32_t)s3 << 24);                \
    }

#define FMA4(A, wc) A.x = fmaf(wc, f0, A.x); A.y = fmaf(wc, f1, A.y); \
                    A.z = fmaf(wc, f2, A.z); A.w = fmaf(wc, f3, A.w);

// ---- SP0 spatial: 4x4 sum-pool * 11 on raw input (t-major z out) ----
__global__ __launch_bounds__(256) void k_pool4(const float* __restrict__ in,
                                               float* __restrict__ z) {
    int idx = blockIdx.x * 256 + threadIdx.x;   // 16384 * 75
    int t4 = idx % T4;
    int n  = idx / T4;                // (b*2+c)*1024 + y*32 + x
    int x = n & 31, y = (n >> 5) & 31, bc = n >> 10;
    const float* base = in + ((size_t)bc * 16384 + (size_t)(4 * y) * 128 + 4 * x) * T_STEPS + 4 * t4;
    float4 acc = {0.f, 0.f, 0.f, 0.f};
#pragma unroll
    for (int i = 0; i < 4; ++i)
#pragma unroll
        for (int j = 0; j < 4; ++j) {
            float4 v = *reinterpret_cast<const float4*>(base + ((size_t)i * 128 + j) * T_STEPS);
            acc.x += v.x; acc.y += v.y; acc.z += v.z; acc.w += v.w;
        }
    float4 o = {11.f * acc.x, 11.f * acc.y, 11.f * acc.z, 11.f * acc.w};
    *reinterpret_cast<float4*>(z + (size_t)n * T_STEPS + 4 * t4) = o;
}

// ---- scan: t-major f32 z in -> u32 spike planes out ----
__global__ __launch_bounds__(256) void k_scan_l0(const float* __restrict__ z,
                                                 uint32_t* __restrict__ sp, int N) {
    int n = blockIdx.x * 256 + threadIdx.x;
    if (n >= N) return;
    const float4* zp = reinterpret_cast<const float4*>(z + (size_t)n * T_STEPS);
    float pp = 0.f, pq = 0.f, rp = 0.f, rq = 0.f;
#pragma unroll 2
    for (int t4 = 0; t4 < T4; ++t4) {
        float4 v = zp[t4];
        uint32_t pack;
        SCAN4(v, pack);
        sp[(size_t)t4 * N + n] = pack;
    }
}

// ---- scan: f4 z planes in -> u32 spike planes out ----
__global__ __launch_bounds__(256) void k_scan_plane(const float4* __restrict__ z,
                                                    uint32_t* __restrict__ sp, int N) {
    int n = blockIdx.x * 256 + threadIdx.x;
    if (n >= N) return;
    float pp = 0.f, pq = 0.f, rp = 0.f, rq = 0.f;
#pragma unroll 2
    for (int t4 = 0; t4 < T4; ++t4) {
        float4 v = z[(size_t)t4 * N + n];
        uint32_t pack;
        SCAN4(v, pack);
        sp[(size_t)t4 * N + n] = pack;
    }
}

// ---- scan: t-major f32 z in -> t-major f32 spikes out (FC tail) ----
__global__ __launch_bounds__(256) void k_scan_f32(const float* __restrict__ z,
                                                  float* __restrict__ s, int N, int ostride) {
    int n = blockIdx.x * blockDim.x + threadIdx.x;
    if (n >= N) return;
    const float4* zp = reinterpret_cast<const float4*>(z + (size_t)n * T_STEPS);
    float* spo = s + (size_t)n * ostride;
    float pp = 0.f, pq = 0.f, rp = 0.f, rq = 0.f;
    for (int it = 0; it < T4; ++it) {
        float4 v = zp[it];
        float4 o;
        scan_step(v.x, pp, pq, rp, rq, o.x);
        scan_step(v.y, pp, pq, rp, rq, o.y);
        scan_step(v.z, pp, pq, rp, rq, o.z);
        scan_step(v.w, pp, pq, rp, rq, o.w);
        *reinterpret_cast<float4*>(spo + it * 4) = o;
    }
}

// ---- fused 2x2 sum-pool * 11 + scan on u32 spike planes (SP1) ----
template<int HW, int NIN, int NOUT>
__global__ __launch_bounds__(256) void k_pool2s(const uint32_t* __restrict__ sin,
                                                uint32_t* __restrict__ sout) {
    int n = blockIdx.x * 256 + threadIdx.x;
    if (n >= NOUT) return;
    int x = n % HW, y = (n / HW) % HW, bc = n / (HW * HW);
    const int W2d = HW * 2;
    const uint32_t* base0 = sin + (size_t)bc * W2d * W2d + (size_t)(2 * y) * W2d + 2 * x;
    float pp = 0.f, pq = 0.f, rp = 0.f, rq = 0.f;
#pragma unroll 2
    for (int t4 = 0; t4 < T4; ++t4) {
        const uint32_t* p = base0 + (size_t)t4 * NIN;
        uint32_t sum = p[0] + p[1] + p[W2d] + p[W2d + 1];  // SWAR, bytes <= 4
        float4 v;
        v.x = 11.f * (float)(sum & 0xffu);
        v.y = 11.f * (float)((sum >> 8) & 0xffu);
        v.z = 11.f * (float)((sum >> 16) & 0xffu);
        v.w = 11.f * (float)(sum >> 24);
        uint32_t pack;
        SCAN4(v, pack);
        sout[(size_t)t4 * NOUT + n] = pack;
    }
}

// ---- SP2: fused 2x2 pool + scan, emits k-major bf16 spikes [b][t_pad=320][2048] ----
__global__ __launch_bounds__(256) void k_pool2s_bf(const uint32_t* __restrict__ sin,
                                                   ushort* __restrict__ sb) {
    int n = blockIdx.x * 256 + threadIdx.x;   // 16384 = b*2048 + k (k = c*64+y*8+x)
    if (n >= 16384) return;
    int x = n & 7, y = (n >> 3) & 7, bc = n >> 6;
    const uint32_t* base0 = sin + (size_t)bc * 256 + (size_t)(2 * y) * 16 + 2 * x;
    int b = n >> 11, k = n & 2047;
    ushort* out = sb + (size_t)b * 320 * 2048 + k;
    float pp = 0.f, pq = 0.f, rp = 0.f, rq = 0.f;
    for (int t4 = 0; t4 < T4; ++t4) {
        const uint32_t* p = base0 + (size_t)t4 * 65536;
        uint32_t sum = p[0] + p[1] + p[16] + p[17];
        float4 v;
        v.x = 11.f * (float)(sum & 0xffu);
        v.y = 11.f * (float)((sum >> 8) & 0xffu);
        v.z = 11.f * (float)((sum >> 16) & 0xffu);
        v.w = 11.f * (float)(sum >> 24);
        float s0, s1, s2, s3;
        scan_step(v.x, pp, pq, rp, rq, s0);
        scan_step(v.y, pp, pq, rp, rq, s1);
        scan_step(v.z, pp, pq, rp, rq, s2);
        scan_step(v.w, pp, pq, rp, rq, s3);
        out[(size_t)(t4 * 4 + 0) * 2048] = s0 != 0.f ? 0x3F80 : 0;
        out[(size_t)(t4 * 4 + 1) * 2048] = s1 != 0.f ? 0x3F80 : 0;
        out[(size_t)(t4 * 4 + 2) * 2048] = s2 != 0.f ? 0x3F80 : 0;
        out[(size_t)(t4 * 4 + 3) * 2048] = s3 != 0.f ? 0x3F80 : 0;
    }
}

// ---- SC1: 5x5 conv 2->16 over 32x32; thread = (b,pix,t4), ALL 16 o in regs ----
__global__ __launch_bounds__(256) void k_conv1(const uint32_t* __restrict__ s0p,
                                               const float* __restrict__ W1,
                                               float4* __restrict__ z1p) {
    __shared__ float w_lds[2][25][16];
    int bid = blockIdx.x;               // 2400
    int pixblk = bid & 3;
    int t4 = (bid >> 2) % 75;
    int b  = bid / 300;
    int tid = threadIdx.x;
    for (int j = tid; j < 800; j += 256) {
        int o = j & 15, kk = (j >> 4) % 25, c = j / 400;
        w_lds[c][kk][o] = W1[(o * 2 + c) * 25 + kk];
    }
    __syncthreads();
    int pix = pixblk * 256 + tid;
    int px = pix & 31, py = pix >> 5;
    float4 acc[16];
#pragma unroll
    for (int o = 0; o < 16; ++o) acc[o] = make_float4(0.f, 0.f, 0.f, 0.f);
    const uint32_t* pb = s0p + (size_t)t4 * 16384 + (size_t)(b * 2) * 1024;
    for (int c = 0; c < 2; ++c) {
#pragma unroll
        for (int ky = 0; ky < 5; ++ky) {
            int yy = py + ky - 2;
            bool rok = (unsigned)yy < 32u;
#pragma unroll
            for (int kx = 0; kx < 5; ++kx) {
                int xx = px + kx - 2;
                uint32_t v = 0;
                if (rok && (unsigned)xx < 32u) v = pb[c * 1024 + yy * 32 + xx];
                float f0 = (float)(v & 0xffu), f1 = (float)((v >> 8) & 0xffu);
                float f2 = (float)((v >> 16) & 0xffu), f3 = (float)(v >> 24);
                int kk = ky * 5 + kx;
#pragma unroll
                for (int oo = 0; oo < 4; ++oo) {
                    float4 w4 = *reinterpret_cast<const float4*>(&w_lds[c][kk][oo * 4]);
                    FMA4(acc[oo * 4 + 0], w4.x);
                    FMA4(acc[oo * 4 + 1], w4.y);
                    FMA4(acc[oo * 4 + 2], w4.z);
                    FMA4(acc[oo * 4 + 3], w4.w);
                }
            }
        }
    }
    size_t zb = (size_t)t4 * 131072 + (size_t)(b * 16) * 1024 + pix;
#pragma unroll
    for (int o = 0; o < 16; ++o) z1p[zb + o * 1024] = acc[o];
}

// ---- SC2: 3x3 conv 16->32 over 16x16; thread = (b,pix,t4), 16 o per half ----
__global__ __launch_bounds__(256) void k_conv2(const uint32_t* __restrict__ s2p,
                                               const float* __restrict__ W2,
                                               float4* __restrict__ z2p) {
    __shared__ float w_lds[16][9][16];
    int bid = blockIdx.x;               // 1200
    int oh = bid & 1;
    int t4 = (bid >> 1) % 75;
    int b  = bid / 150;
    int tid = threadIdx.x;              // pix (16x16)
    for (int j = tid; j < 2304; j += 256) {
        int o = j & 15;
        int t9 = (j >> 4) % 9;
        int c  = j / 144;
        w_lds[c][t9][o] = W2[(size_t)((oh * 16 + o) * 16 + c) * 9 + t9];
    }
    __syncthreads();
    int px = tid & 15, py = tid >> 4;
    float4 acc[16];
#pragma unroll
    for (int o = 0; o < 16; ++o) acc[o] = make_float4(0.f, 0.f, 0.f, 0.f);
    const uint32_t* pb = s2p + (size_t)t4 * 32768 + (size_t)(b * 16) * 256;
    for (int c = 0; c < 16; ++c) {
#pragma unroll
        for (int ky = 0; ky < 3; ++ky) {
            int yy = py + ky - 1;
            bool rok = (unsigned)yy < 16u;
#pragma unroll
            for (int kx = 0; kx < 3; ++kx) {
                int xx = px + kx - 1;
                uint32_t v = 0;
                if (rok && (unsigned)xx < 16u) v = pb[c * 256 + yy * 16 + xx];
                float f0 = (float)(v & 0xffu), f1 = (float)((v >> 8) & 0xffu);
                float f2 = (float)((v >> 16) & 0xffu), f3 = (float)(v >> 24);
                int t9 = ky * 3 + kx;
#pragma unroll
                for (int oo = 0; oo < 4; ++oo) {
                    float4 w4 = *reinterpret_cast<const float4*>(&w_lds[c][t9][oo * 4]);
                    FMA4(acc[oo * 4 + 0], w4.x);
                    FMA4(acc[oo * 4 + 1], w4.y);
                    FMA4(acc[oo * 4 + 2], w4.z);
                    FMA4(acc[oo * 4 + 3], w4.w);
                }
            }
        }
    }
    size_t zb = (size_t)t4 * 65536 + (size_t)(b * 32 + oh * 16) * 256 + tid;
#pragma unroll
    for (int o = 0; o < 16; ++o) z2p[zb + o * 256] = acc[o];
}

// ---- Wf1 3-way bf16 split: w = h + m + l (RNE at each stage) ----
__device__ __forceinline__ ushort f2bf(float f) {
    uint32_t u = __float_as_uint(f);
    u = u + 0x7fffu + ((u >> 16) & 1u);
    return (ushort)(u >> 16);
}
__device__ __forceinline__ float bf2f(ushort h) {
    return __uint_as_float((uint32_t)h << 16);
}
__global__ __launch_bounds__(256) void k_wsplit(const float* __restrict__ W,
                                                ushort* __restrict__ Wh,
                                                ushort* __restrict__ Wm,
                                                ushort* __restrict__ Wl, int n) {
    int i = blockIdx.x * 256 + threadIdx.x;
    if (i >= n) return;
    float w = W[i];
    ushort h = f2bf(w);
    float r1 = w - bf2f(h);
    ushort m = f2bf(r1);
    float r2 = r1 - bf2f(m);
    ushort l = f2bf(r2);
    Wh[i] = h; Wm[i] = m; Wl[i] = l;
}

// ---- SF1: LDS-tiled bf16 MFMA GEMM (3-split weights, exact {0,1} spikes) ----
// Block = 4 waves, tile 64o x 64t, BK=32, double-buffered LDS (32 KB).
// Wave (wv&1 -> o-half, wv>>1 -> t-half) computes 32o x 32t = 2x2 MFMA frags.
// LDS layout: 16 slots (12 = 3 planes x 4 k-chunks of A, 4 = B k-chunks),
// each slot = 64 rows x 16B -> ds_read_b128 walks 256B contiguous per 16
// lanes (conflict-free, no swizzle). Staging: reg (uint4 x4/thread) with
// next-k loads issued before the barrier (fly during MFMA).
// Grid 320: obk = bid&7 pins each o-tile's W slice (786 KB x3 planes... 786KB
// total bf16) to one XCD's L2; spikes stream via L3.
__global__ __launch_bounds__(256) void k_fc1_mfma(const ushort* __restrict__ Wh,
                                                  const ushort* __restrict__ Wm,
                                                  const ushort* __restrict__ Wl,
                                                  const ushort* __restrict__ sb,
                                                  float* __restrict__ z) {
    __shared__ ushort lds[2][16 * 64 * 8];   // 2 x 16KB

    int bid = blockIdx.x;                    // 320
    int obk = bid & 7;                       // XCD-pinned o-tile
    int combo = bid >> 3;                    // 0..39
    int tbk = combo % 5;
    int b   = combo / 5;
    int tid = threadIdx.x;
    int wv = tid >> 6, lane = tid & 63, l15 = lane & 15, l4 = lane >> 4;
    int o0 = obk * 64, t0 = tbk * 64;

    // staging: thread handles 4 cells (slot s = wv*4+u, row r = lane)
    const ushort* gsrc[4];
    int ldsoff[4];
    {
        const ushort* Wpl[3] = {Wh, Wm, Wl};
        int r = lane;
#pragma unroll
        for (int u = 0; u < 4; ++u) {
            int s = wv * 4 + u;
            if (s < 12) {
                int p = s >> 2, q = s & 3;
                gsrc[u] = Wpl[p] + (size_t)(o0 + r) * 2048 + q * 8;
            } else {
                int q = s - 12;
                gsrc[u] = sb + ((size_t)b * 320 + t0 + r) * 2048 + q * 8;
            }
            ldsoff[u] = (s * 64 + r) * 8;
        }
    }

    // reader offsets (ushort indices)
    int rowA = (wv & 1) * 32 + l15;
    int rowB = (wv >> 1) * 32 + l15;
    int idxA[3][2], idxB[2];
#pragma unroll
    for (int p = 0; p < 3; ++p)
#pragma unroll
        for (int i = 0; i < 2; ++i)
            idxA[p][i] = ((p * 4 + l4) * 64 + rowA + i * 16) * 8;
#pragma unroll
    for (int j = 0; j < 2; ++j)
        idxB[j] = ((12 + l4) * 64 + rowB + j * 16) * 8;

    f32x4 acc00 = {0,0,0,0}, acc01 = {0,0,0,0}, acc10 = {0,0,0,0}, acc11 = {0,0,0,0};

    uint4 rv[4];
#pragma unroll
    for (int u = 0; u < 4; ++u)
        rv[u] = *reinterpret_cast<const uint4*>(gsrc[u]);

    int buf = 0;
    for (int ks = 0; ks < 64; ++ks) {
        // write staged regs (compiler inserts vmcnt wait on rv deps)
#pragma unroll
        for (int u = 0; u < 4; ++u)
            *reinterpret_cast<uint4*>(&lds[buf][ldsoff[u]]) = rv[u];
        // issue next k-step loads; they stay in flight across barrier+MFMA
        if (ks < 63) {
            int koff = (ks + 1) * 32;
#pragma unroll
            for (int u = 0; u < 4; ++u)
                rv[u] = *reinterpret_cast<const uint4*>(gsrc[u] + koff);
        }
        __syncthreads();     // lds[buf] visible; buf^1 safe to overwrite next iter
        bf16x8 B0 = *reinterpret_cast<const bf16x8*>(&lds[buf][idxB[0]]);
        bf16x8 B1 = *reinterpret_cast<const bf16x8*>(&lds[buf][idxB[1]]);
#pragma unroll
        for (int p = 0; p < 3; ++p) {
            bf16x8 A0 = *reinterpret_cast<const bf16x8*>(&lds[buf][idxA[p][0]]);
            bf16x8 A1 = *reinterpret_cast<const bf16x8*>(&lds[buf][idxA[p][1]]);
            acc00 = __builtin_amdgcn_mfma_f32_16x16x32_bf16(A0, B0, acc00, 0, 0, 0);
            acc01 = __builtin_amdgcn_mfma_f32_16x16x32_bf16(A0, B1, acc01, 0, 0, 0);
            acc10 = __builtin_amdgcn_mfma_f32_16x16x32_bf16(A1, B0, acc10, 0, 0, 0);
            acc11 = __builtin_amdgcn_mfma_f32_16x16x32_bf16(A1, B1, acc11, 0, 0, 0);
        }
        buf ^= 1;
    }

    // C store: D col = l15 (t), D row = l4*4 + reg (o within 16-subtile)
    int ob = o0 + (wv & 1) * 32 + l4 * 4;
    int tb = t0 + (wv >> 1) * 32 + l15;
#pragma unroll
    for (int i = 0; i < 2; ++i) {
        f32x4 ai0 = (i == 0) ? acc00 : acc10;
        f32x4 ai1 = (i == 0) ? acc01 : acc11;
#pragma unroll
        for (int j = 0; j < 2; ++j) {
            f32x4 a = (j == 0) ? ai0 : ai1;
            int tcol = tb + j * 16;
            if (tcol < T_STEPS) {
                float* zr = z + ((size_t)b * 512 + ob + i * 16) * T_STEPS + tcol;
                zr[0 * T_STEPS] = a.x;
                zr[1 * T_STEPS] = a.y;
                zr[2 * T_STEPS] = a.z;
                zr[3 * T_STEPS] = a.w;
            }
        }
    }
}

// ---- SF2: 512 -> 11 FC (t-major f32 spikes) ----
__global__ __launch_bounds__(256) void k_fc2(const float* __restrict__ s5,
                                             const float* __restrict__ Wf2,
                                             float* __restrict__ z) {
    int idx = blockIdx.x * 256 + threadIdx.x;   // 11*8*75 = 6600
    if (idx >= 6600) return;
    int t4 = idx % T4;
    int r  = idx / T4;            // o*8 + b
    int b = r & 7, o = r >> 3;
    const float* sp = s5 + (size_t)b * 512 * T_STEPS + 4 * t4;
    const float* wp = Wf2 + (size_t)o * 512;
    float a0 = 0.f, a1 = 0.f, a2 = 0.f, a3 = 0.f;
#pragma unroll 2
    for (int k = 0; k < 512; k += 4) {
        float4 wv = *reinterpret_cast<const float4*>(wp + k);
        float4 v0 = *reinterpret_cast<const float4*>(sp + (size_t)(k + 0) * T_STEPS);
        float4 v1 = *reinterpret_cast<const float4*>(sp + (size_t)(k + 1) * T_STEPS);
        float4 v2 = *reinterpret_cast<const float4*>(sp + (size_t)(k + 2) * T_STEPS);
        float4 v3 = *reinterpret_cast<const float4*>(sp + (size_t)(k + 3) * T_STEPS);
        a0 = fmaf(wv.x, v0.x, a0); a1 = fmaf(wv.x, v0.y, a1); a2 = fmaf(wv.x, v0.z, a2); a3 = fmaf(wv.x, v0.w, a3);
        a0 = fmaf(wv.y, v1.x, a0); a1 = fmaf(wv.y, v1.y, a1); a2 = fmaf(wv.y, v1.z, a2); a3 = fmaf(wv.y, v1.w, a3);
        a0 = fmaf(wv.z, v2.x, a0); a1 = fmaf(wv.z, v2.y, a1); a2 = fmaf(wv.z, v2.z, a2); a3 = fmaf(wv.z, v2.w, a3);
        a0 = fmaf(wv.w, v3.x, a0); a1 = fmaf(wv.w, v3.y, a1); a2 = fmaf(wv.w, v3.z, a2); a3 = fmaf(wv.w, v3.w, a3);
    }
    *reinterpret_cast<float4*>(z + (size_t)(b * 11 + o) * T_STEPS + 4 * t4) = make_float4(a0, a1, a2, a3);
}

__global__ void k_zero(float* out, int n) {
    int i = blockIdx.x * 256 + threadIdx.x;
    if (i < n) out[i] = 0.f;
}

extern "C" void kernel_launch(void* const* d_in, const int* in_sizes, int n_in,
                              void* d_out, int out_size, void* d_ws, size_t ws_size,
                              hipStream_t stream) {
    const float* s_in = (const float*)d_in[0];
    const float* W1   = (const float*)d_in[1];
    const float* W2   = (const float*)d_in[2];
    const float* Wf1  = (const float*)d_in[3];
    const float* Wf2  = (const float*)d_in[4];
    float* out = (float*)d_out;

    const size_t OFF_Z  = 0;               // max 157,286,400 (conv1 z planes)
    const size_t OFF_S0 = 157286400;       // u32 planes,  4,915,200
    const size_t OFF_S1 = 162201600;       // u32 planes, 39,321,600
    const size_t OFF_S2 = 201523200;       // u32 planes,  9,830,400
    const size_t OFF_S3 = 211353600;       // u32 planes, 19,660,800
    const size_t OFF_SB = 231014400;       // bf16 [8][320][2048] = 10,485,760
    const size_t OFF_S5 = 241500160;       // f32 t-major, 4,915,200
    const size_t OFF_WH = 246415360;       // bf16 512x2048 = 2,097,152
    const size_t OFF_WM = 248512512;
    const size_t OFF_WL = 250609664;
    const size_t NEEDED = 252706816;

    if (ws_size < NEEDED) {
        k_zero<<<(26400 + 255) / 256, 256, 0, stream>>>(out, 26400);
        return;
    }

    char* ws = (char*)d_ws;
    float*    Z   = (float*)(ws + OFF_Z);
    uint32_t* s0p = (uint32_t*)(ws + OFF_S0);
    uint32_t* s1p = (uint32_t*)(ws + OFF_S1);
    uint32_t* s2p = (uint32_t*)(ws + OFF_S2);
    uint32_t* s3p = (uint32_t*)(ws + OFF_S3);
    ushort*   sbf = (ushort*)(ws + OFF_SB);
    float*    s5  = (float*)(ws + OFF_S5);
    ushort*   Wh  = (ushort*)(ws + OFF_WH);
    ushort*   Wm  = (ushort*)(ws + OFF_WM);
    ushort*   Wl  = (ushort*)(ws + OFF_WL);

    // Wf1 split (independent of the pipeline; 1M elems)
    k_wsplit<<<4096, 256, 0, stream>>>(Wf1, Wh, Wm, Wl, 512 * 2048);

    // SP0: pool4 (t-major z) + scan -> u32 planes
    k_pool4<<<4800, 256, 0, stream>>>(s_in, Z);
    k_scan_l0<<<64, 256, 0, stream>>>(Z, s0p, 16384);

    // SC1: conv 5x5 (2->16), all-o-in-regs -> z planes; scan -> s1p
    k_conv1<<<2400, 256, 0, stream>>>(s0p, W1, (float4*)Z);
    k_scan_plane<<<512, 256, 0, stream>>>((const float4*)Z, s1p, 131072);

    // SP1: fused pool2+scan (32x32 -> 16x16, 128 bc)
    k_pool2s<16, 131072, 32768><<<128, 256, 0, stream>>>(s1p, s2p);

    // SC2: conv 3x3 (16->32), 16-o halves -> z planes; scan -> s3p
    k_conv2<<<1200, 256, 0, stream>>>(s2p, W2, (float4*)Z);
    k_scan_plane<<<256, 256, 0, stream>>>((const float4*)Z, s3p, 65536);

    // SP2: fused pool2+scan -> k-major bf16 spikes [b][320][2048]
    k_pool2s_bf<<<64, 256, 0, stream>>>(s3p, sbf);

    // SF1: LDS-tiled bf16-MFMA GEMM -> t-major z; scan -> s5
    k_fc1_mfma<<<320, 256, 0, stream>>>(Wh, Wm, Wl, sbf, Z);
    k_scan_f32<<<16, 256, 0, stream>>>(Z, s5, 4096, 300);

    // SF2: FC 512->11 + final scan into d_out
    k_fc2<<<26, 256, 0, stream>>>(s5, Wf2, Z);
    k_scan_f32<<<1, 128, 0, stream>>>(Z, out, 88, 300);
}

// Round 9
// 888.999 us; speedup vs baseline: 4.7636x; 1.1230x over previous
//
#include <hip/hip_runtime.h>
#include <stdint.h>

#define T_STEPS 300
#define T4 75

typedef __attribute__((ext_vector_type(8))) short bf16x8;
typedef __attribute__((ext_vector_type(4))) float f32x4;

// ---- scan (psp + spike) constants: d = exp(-1), c = e, cr = -2*theta*e ----
__device__ __forceinline__ void scan_step(float x, float& pp, float& pq,
                                          float& rp, float& rq, float& s_out) {
    const float D  = 0.36787944117144233f;
    const float C  = 2.7182818284590452f;
    const float CR = -54.365636569180904f;
    const float TH = 10.0f;
    pq = D * (pq + pp);      // psp state (q uses old p)
    pp = D * pp + x;
    float u = C * pq;
    rq = D * (rq + rp);      // refractory state
    float s = (u + CR * rq >= TH) ? 1.0f : 0.0f;
    rp = D * rp + s;
    s_out = s;
}

#define SCAN4(v, PACK)                                                     \
    {                                                                      \
        float s0, s1, s2, s3;                                              \
        scan_step(v.x, pp, pq, rp, rq, s0);                                \
        scan_step(v.y, pp, pq, rp, rq, s1);                                \
        scan_step(v.z, pp, pq, rp, rq, s2);                                \
        scan_step(v.w, pp, pq, rp, rq, s3);                                \
        PACK = (uint32_t)s0 | ((uint32_t)s1 << 8) |                        \
               ((uint32_t)s2 << 16) | ((uint32_t)s3 << 24);                \
    }

#define FMA4(A, wc) A.x = fmaf(wc, f0, A.x); A.y = fmaf(wc, f1, A.y); \
                    A.z = fmaf(wc, f2, A.z); A.w = fmaf(wc, f3, A.w);

// ---- SP0 spatial: 4x4 sum-pool * 11 on raw input (t-major z out) ----
__global__ __launch_bounds__(256) void k_pool4(const float* __restrict__ in,
                                               float* __restrict__ z) {
    int idx = blockIdx.x * 256 + threadIdx.x;   // 16384 * 75
    int t4 = idx % T4;
    int n  = idx / T4;                // (b*2+c)*1024 + y*32 + x
    int x = n & 31, y = (n >> 5) & 31, bc = n >> 10;
    const float* base = in + ((size_t)bc * 16384 + (size_t)(4 * y) * 128 + 4 * x) * T_STEPS + 4 * t4;
    float4 acc = {0.f, 0.f, 0.f, 0.f};
#pragma unroll
    for (int i = 0; i < 4; ++i)
#pragma unroll
        for (int j = 0; j < 4; ++j) {
            float4 v = *reinterpret_cast<const float4*>(base + ((size_t)i * 128 + j) * T_STEPS);
            acc.x += v.x; acc.y += v.y; acc.z += v.z; acc.w += v.w;
        }
    float4 o = {11.f * acc.x, 11.f * acc.y, 11.f * acc.z, 11.f * acc.w};
    *reinterpret_cast<float4*>(z + (size_t)n * T_STEPS + 4 * t4) = o;
}

// ---- scan: t-major f32 z in -> u32 spike planes out ----
__global__ __launch_bounds__(256) void k_scan_l0(const float* __restrict__ z,
                                                 uint32_t* __restrict__ sp, int N) {
    int n = blockIdx.x * 256 + threadIdx.x;
    if (n >= N) return;
    const float4* zp = reinterpret_cast<const float4*>(z + (size_t)n * T_STEPS);
    float pp = 0.f, pq = 0.f, rp = 0.f, rq = 0.f;
#pragma unroll 2
    for (int t4 = 0; t4 < T4; ++t4) {
        float4 v = zp[t4];
        uint32_t pack;
        SCAN4(v, pack);
        sp[(size_t)t4 * N + n] = pack;
    }
}

// ---- scan: f4 z planes in -> u32 spike planes out ----
__global__ __launch_bounds__(256) void k_scan_plane(const float4* __restrict__ z,
                                                    uint32_t* __restrict__ sp, int N) {
    int n = blockIdx.x * 256 + threadIdx.x;
    if (n >= N) return;
    float pp = 0.f, pq = 0.f, rp = 0.f, rq = 0.f;
#pragma unroll 2
    for (int t4 = 0; t4 < T4; ++t4) {
        float4 v = z[(size_t)t4 * N + n];
        uint32_t pack;
        SCAN4(v, pack);
        sp[(size_t)t4 * N + n] = pack;
    }
}

// ---- scan: t-major f32 z in -> t-major f32 spikes out (FC tail) ----
__global__ __launch_bounds__(256) void k_scan_f32(const float* __restrict__ z,
                                                  float* __restrict__ s, int N, int ostride) {
    int n = blockIdx.x * blockDim.x + threadIdx.x;
    if (n >= N) return;
    const float4* zp = reinterpret_cast<const float4*>(z + (size_t)n * T_STEPS);
    float* spo = s + (size_t)n * ostride;
    float pp = 0.f, pq = 0.f, rp = 0.f, rq = 0.f;
    for (int it = 0; it < T4; ++it) {
        float4 v = zp[it];
        float4 o;
        scan_step(v.x, pp, pq, rp, rq, o.x);
        scan_step(v.y, pp, pq, rp, rq, o.y);
        scan_step(v.z, pp, pq, rp, rq, o.z);
        scan_step(v.w, pp, pq, rp, rq, o.w);
        *reinterpret_cast<float4*>(spo + it * 4) = o;
    }
}

// ---- fused 2x2 sum-pool * 11 + scan on u32 spike planes (SP1) ----
template<int HW, int NIN, int NOUT>
__global__ __launch_bounds__(256) void k_pool2s(const uint32_t* __restrict__ sin,
                                                uint32_t* __restrict__ sout) {
    int n = blockIdx.x * 256 + threadIdx.x;
    if (n >= NOUT) return;
    int x = n % HW, y = (n / HW) % HW, bc = n / (HW * HW);
    const int W2d = HW * 2;
    const uint32_t* base0 = sin + (size_t)bc * W2d * W2d + (size_t)(2 * y) * W2d + 2 * x;
    float pp = 0.f, pq = 0.f, rp = 0.f, rq = 0.f;
#pragma unroll 2
    for (int t4 = 0; t4 < T4; ++t4) {
        const uint32_t* p = base0 + (size_t)t4 * NIN;
        uint32_t sum = p[0] + p[1] + p[W2d] + p[W2d + 1];  // SWAR, bytes <= 4
        float4 v;
        v.x = 11.f * (float)(sum & 0xffu);
        v.y = 11.f * (float)((sum >> 8) & 0xffu);
        v.z = 11.f * (float)((sum >> 16) & 0xffu);
        v.w = 11.f * (float)(sum >> 24);
        uint32_t pack;
        SCAN4(v, pack);
        sout[(size_t)t4 * NOUT + n] = pack;
    }
}

// ---- SP2: fused 2x2 pool + scan -> spikes in B-FRAGMENT layout ----
// sf[b][T=t>>4][ks=k>>5][lane][8] with lane = ((k>>3)&3)*16 + (t&15), elem j = k&7.
// Makes every fc1 B-load a lane-linear (fully coalesced) 1KB wave load.
__global__ __launch_bounds__(256) void k_pool2s_bf(const uint32_t* __restrict__ sin,
                                                   ushort* __restrict__ sf) {
    int n = blockIdx.x * 256 + threadIdx.x;   // 16384 = b*2048 + k (k = c*64+y*8+x)
    if (n >= 16384) return;
    int x = n & 7, y = (n >> 3) & 7, bc = n >> 6;
    const uint32_t* base0 = sin + (size_t)bc * 256 + (size_t)(2 * y) * 16 + 2 * x;
    int b = n >> 11, k = n & 2047;
    // k-dependent (fixed per thread) part of the fragment address
    size_t kpart = ((size_t)(k >> 5)) * 512 + (size_t)((k >> 3) & 3) * 128 + (k & 7);
    ushort* outb = sf + (size_t)b * 20 * 64 * 512 + kpart;
    float pp = 0.f, pq = 0.f, rp = 0.f, rq = 0.f;
    for (int t4 = 0; t4 < T4; ++t4) {
        const uint32_t* p = base0 + (size_t)t4 * 65536;
        uint32_t sum = p[0] + p[1] + p[16] + p[17];
        float4 v;
        v.x = 11.f * (float)(sum & 0xffu);
        v.y = 11.f * (float)((sum >> 8) & 0xffu);
        v.z = 11.f * (float)((sum >> 16) & 0xffu);
        v.w = 11.f * (float)(sum >> 24);
        float s0, s1, s2, s3;
        scan_step(v.x, pp, pq, rp, rq, s0);
        scan_step(v.y, pp, pq, rp, rq, s1);
        scan_step(v.z, pp, pq, rp, rq, s2);
        scan_step(v.w, pp, pq, rp, rq, s3);
        float sv[4] = {s0, s1, s2, s3};
#pragma unroll
        for (int r = 0; r < 4; ++r) {
            int t = t4 * 4 + r;
            outb[((size_t)(t >> 4) * 64) * 512 + (size_t)(t & 15) * 8] =
                sv[r] != 0.f ? (ushort)0x3F80 : (ushort)0;
        }
    }
}

// ---- SC1: 5x5 conv 2->16 over 32x32; thread = (b,pix,t4), ALL 16 o in regs ----
__global__ __launch_bounds__(256) void k_conv1(const uint32_t* __restrict__ s0p,
                                               const float* __restrict__ W1,
                                               float4* __restrict__ z1p) {
    __shared__ float w_lds[2][25][16];
    int bid = blockIdx.x;               // 2400
    int pixblk = bid & 3;
    int t4 = (bid >> 2) % 75;
    int b  = bid / 300;
    int tid = threadIdx.x;
    for (int j = tid; j < 800; j += 256) {
        int o = j & 15, kk = (j >> 4) % 25, c = j / 400;
        w_lds[c][kk][o] = W1[(o * 2 + c) * 25 + kk];
    }
    __syncthreads();
    int pix = pixblk * 256 + tid;
    int px = pix & 31, py = pix >> 5;
    float4 acc[16];
#pragma unroll
    for (int o = 0; o < 16; ++o) acc[o] = make_float4(0.f, 0.f, 0.f, 0.f);
    const uint32_t* pb = s0p + (size_t)t4 * 16384 + (size_t)(b * 2) * 1024;
    for (int c = 0; c < 2; ++c) {
#pragma unroll
        for (int ky = 0; ky < 5; ++ky) {
            int yy = py + ky - 2;
            bool rok = (unsigned)yy < 32u;
#pragma unroll
            for (int kx = 0; kx < 5; ++kx) {
                int xx = px + kx - 2;
                uint32_t v = 0;
                if (rok && (unsigned)xx < 32u) v = pb[c * 1024 + yy * 32 + xx];
                float f0 = (float)(v & 0xffu), f1 = (float)((v >> 8) & 0xffu);
                float f2 = (float)((v >> 16) & 0xffu), f3 = (float)(v >> 24);
                int kk = ky * 5 + kx;
#pragma unroll
                for (int oo = 0; oo < 4; ++oo) {
                    float4 w4 = *reinterpret_cast<const float4*>(&w_lds[c][kk][oo * 4]);
                    FMA4(acc[oo * 4 + 0], w4.x);
                    FMA4(acc[oo * 4 + 1], w4.y);
                    FMA4(acc[oo * 4 + 2], w4.z);
                    FMA4(acc[oo * 4 + 3], w4.w);
                }
            }
        }
    }
    size_t zb = (size_t)t4 * 131072 + (size_t)(b * 16) * 1024 + pix;
#pragma unroll
    for (int o = 0; o < 16; ++o) z1p[zb + o * 1024] = acc[o];
}

// ---- SC2: 3x3 conv 16->32 over 16x16; thread = (b,pix,t4), 16 o per half ----
__global__ __launch_bounds__(256) void k_conv2(const uint32_t* __restrict__ s2p,
                                               const float* __restrict__ W2,
                                               float4* __restrict__ z2p) {
    __shared__ float w_lds[16][9][16];
    int bid = blockIdx.x;               // 1200
    int oh = bid & 1;
    int t4 = (bid >> 1) % 75;
    int b  = bid / 150;
    int tid = threadIdx.x;              // pix (16x16)
    for (int j = tid; j < 2304; j += 256) {
        int o = j & 15;
        int t9 = (j >> 4) % 9;
        int c  = j / 144;
        w_lds[c][t9][o] = W2[(size_t)((oh * 16 + o) * 16 + c) * 9 + t9];
    }
    __syncthreads();
    int px = tid & 15, py = tid >> 4;
    float4 acc[16];
#pragma unroll
    for (int o = 0; o < 16; ++o) acc[o] = make_float4(0.f, 0.f, 0.f, 0.f);
    const uint32_t* pb = s2p + (size_t)t4 * 32768 + (size_t)(b * 16) * 256;
    for (int c = 0; c < 16; ++c) {
#pragma unroll
        for (int ky = 0; ky < 3; ++ky) {
            int yy = py + ky - 1;
            bool rok = (unsigned)yy < 16u;
#pragma unroll
            for (int kx = 0; kx < 3; ++kx) {
                int xx = px + kx - 1;
                uint32_t v = 0;
                if (rok && (unsigned)xx < 16u) v = pb[c * 256 + yy * 16 + xx];
                float f0 = (float)(v & 0xffu), f1 = (float)((v >> 8) & 0xffu);
                float f2 = (float)((v >> 16) & 0xffu), f3 = (float)(v >> 24);
                int t9 = ky * 3 + kx;
#pragma unroll
                for (int oo = 0; oo < 4; ++oo) {
                    float4 w4 = *reinterpret_cast<const float4*>(&w_lds[c][t9][oo * 4]);
                    FMA4(acc[oo * 4 + 0], w4.x);
                    FMA4(acc[oo * 4 + 1], w4.y);
                    FMA4(acc[oo * 4 + 2], w4.z);
                    FMA4(acc[oo * 4 + 3], w4.w);
                }
            }
        }
    }
    size_t zb = (size_t)t4 * 65536 + (size_t)(b * 32 + oh * 16) * 256 + tid;
#pragma unroll
    for (int o = 0; o < 16; ++o) z2p[zb + o * 256] = acc[o];
}

// ---- Wf1: 3-way bf16 split + A-FRAGMENT layout ----
// Wf[plane][R=o>>4][ks=k>>5][lane][8], lane = ((k>>3)&3)*16 + (o&15), j = k&7.
__device__ __forceinline__ ushort f2bf(float f) {
    uint32_t u = __float_as_uint(f);
    u = u + 0x7fffu + ((u >> 16) & 1u);   // round-to-nearest-even
    return (ushort)(u >> 16);
}
__device__ __forceinline__ float bf2f(ushort h) {
    return __uint_as_float((uint32_t)h << 16);
}
__global__ __launch_bounds__(256) void k_wfrag(const float* __restrict__ W,
                                               ushort* __restrict__ Wf) {
    int i = blockIdx.x * 256 + threadIdx.x;   // 512*2048
    int o = i >> 11, k = i & 2047;
    float w = W[i];
    ushort h = f2bf(w);
    float r1 = w - bf2f(h);
    ushort m = f2bf(r1);
    float r2 = r1 - bf2f(m);
    ushort l = f2bf(r2);
    int lane = (((k >> 3) & 3) << 4) | (o & 15);
    size_t base = (((size_t)(o >> 4)) * 64 + (k >> 5)) * 512 + lane * 8 + (k & 7);
    const size_t PL = (size_t)32 * 64 * 512;
    Wf[base] = h;
    Wf[PL + base] = m;
    Wf[2 * PL + base] = l;
}

// ---- SF1: fragment-layout bf16 MFMA GEMM. No LDS, no barriers. ----
// Wave = 16o x 32t; 640 blocks x 4 waves = 2560 waves (2.5/SIMD).
// Every operand load: base + ks*512 + lane*8 -> contiguous 1KB per wave instr.
// R = gw&31: with round-robin block->XCD dispatch, XCD x sees only R in
// {4x..4x+3} -> 768KB of W resident per XCD L2.
__device__ __forceinline__ bf16x8 ldb(const ushort* p) {
    return *reinterpret_cast<const bf16x8*>(p);
}
__global__ __launch_bounds__(256) void k_fc1_frag(const ushort* __restrict__ Wf,
                                                  const ushort* __restrict__ sf,
                                                  float* __restrict__ z) {
    int wv = threadIdx.x >> 6, lane = threadIdx.x & 63;
    int gw = blockIdx.x * 4 + wv;          // 0..2559
    int R  = gw & 31;
    int combo = gw >> 5;                   // 0..79
    int tp = combo % 10, b = combo / 10;
    int l15 = lane & 15, l4 = lane >> 4;

    const size_t PL = (size_t)32 * 64 * 512;
    const ushort* A0p = Wf + ((size_t)R * 64) * 512 + lane * 8;
    const ushort* A1p = A0p + PL;
    const ushort* A2p = A0p + 2 * PL;
    const ushort* B0p = sf + ((size_t)(b * 20 + 2 * tp + 0) * 64) * 512 + lane * 8;
    const ushort* B1p = B0p + (size_t)64 * 512;

    f32x4 acc0 = {0.f, 0.f, 0.f, 0.f};
    f32x4 acc1 = {0.f, 0.f, 0.f, 0.f};

    bf16x8 a0 = ldb(A0p), a1 = ldb(A1p), a2 = ldb(A2p);
    bf16x8 b0 = ldb(B0p), b1 = ldb(B1p);

    for (int ks = 0; ks < 64; ++ks) {
        int kn = (ks < 63) ? (ks + 1) * 512 : 0;   // last prefetch redundant
        bf16x8 na0 = ldb(A0p + kn), na1 = ldb(A1p + kn), na2 = ldb(A2p + kn);
        bf16x8 nb0 = ldb(B0p + kn), nb1 = ldb(B1p + kn);
        acc0 = __builtin_amdgcn_mfma_f32_16x16x32_bf16(a0, b0, acc0, 0, 0, 0);
        acc1 = __builtin_amdgcn_mfma_f32_16x16x32_bf16(a0, b1, acc1, 0, 0, 0);
        acc0 = __builtin_amdgcn_mfma_f32_16x16x32_bf16(a1, b0, acc0, 0, 0, 0);
        acc1 = __builtin_amdgcn_mfma_f32_16x16x32_bf16(a1, b1, acc1, 0, 0, 0);
        acc0 = __builtin_amdgcn_mfma_f32_16x16x32_bf16(a2, b0, acc0, 0, 0, 0);
        acc1 = __builtin_amdgcn_mfma_f32_16x16x32_bf16(a2, b1, acc1, 0, 0, 0);
        a0 = na0; a1 = na1; a2 = na2; b0 = nb0; b1 = nb1;
    }

    // C/D: col = l15 (t), row = l4*4 + reg (o within 16-subtile)
    int orow = R * 16 + l4 * 4;
    int tb = tp * 32;
    {
        int tc = tb + l15;
        if (tc < T_STEPS) {
            float* zr = z + ((size_t)b * 512 + orow) * T_STEPS + tc;
            zr[0 * T_STEPS] = acc0.x; zr[1 * T_STEPS] = acc0.y;
            zr[2 * T_STEPS] = acc0.z; zr[3 * T_STEPS] = acc0.w;
        }
    }
    {
        int tc = tb + 16 + l15;
        if (tc < T_STEPS) {
            float* zr = z + ((size_t)b * 512 + orow) * T_STEPS + tc;
            zr[0 * T_STEPS] = acc1.x; zr[1 * T_STEPS] = acc1.y;
            zr[2 * T_STEPS] = acc1.z; zr[3 * T_STEPS] = acc1.w;
        }
    }
}

// ---- SF2: 512 -> 11 FC (t-major f32 spikes) ----
__global__ __launch_bounds__(256) void k_fc2(const float* __restrict__ s5,
                                             const float* __restrict__ Wf2,
                                             float* __restrict__ z) {
    int idx = blockIdx.x * 256 + threadIdx.x;   // 11*8*75 = 6600
    if (idx >= 6600) return;
    int t4 = idx % T4;
    int r  = idx / T4;            // o*8 + b
    int b = r & 7, o = r >> 3;
    const float* sp = s5 + (size_t)b * 512 * T_STEPS + 4 * t4;
    const float* wp = Wf2 + (size_t)o * 512;
    float a0 = 0.f, a1 = 0.f, a2 = 0.f, a3 = 0.f;
#pragma unroll 2
    for (int k = 0; k < 512; k += 4) {
        float4 wv = *reinterpret_cast<const float4*>(wp + k);
        float4 v0 = *reinterpret_cast<const float4*>(sp + (size_t)(k + 0) * T_STEPS);
        float4 v1 = *reinterpret_cast<const float4*>(sp + (size_t)(k + 1) * T_STEPS);
        float4 v2 = *reinterpret_cast<const float4*>(sp + (size_t)(k + 2) * T_STEPS);
        float4 v3 = *reinterpret_cast<const float4*>(sp + (size_t)(k + 3) * T_STEPS);
        a0 = fmaf(wv.x, v0.x, a0); a1 = fmaf(wv.x, v0.y, a1); a2 = fmaf(wv.x, v0.z, a2); a3 = fmaf(wv.x, v0.w, a3);
        a0 = fmaf(wv.y, v1.x, a0); a1 = fmaf(wv.y, v1.y, a1); a2 = fmaf(wv.y, v1.z, a2); a3 = fmaf(wv.y, v1.w, a3);
        a0 = fmaf(wv.z, v2.x, a0); a1 = fmaf(wv.z, v2.y, a1); a2 = fmaf(wv.z, v2.z, a2); a3 = fmaf(wv.z, v2.w, a3);
        a0 = fmaf(wv.w, v3.x, a0); a1 = fmaf(wv.w, v3.y, a1); a2 = fmaf(wv.w, v3.z, a2); a3 = fmaf(wv.w, v3.w, a3);
    }
    *reinterpret_cast<float4*>(z + (size_t)(b * 11 + o) * T_STEPS + 4 * t4) = make_float4(a0, a1, a2, a3);
}

__global__ void k_zero(float* out, int n) {
    int i = blockIdx.x * 256 + threadIdx.x;
    if (i < n) out[i] = 0.f;
}

extern "C" void kernel_launch(void* const* d_in, const int* in_sizes, int n_in,
                              void* d_out, int out_size, void* d_ws, size_t ws_size,
                              hipStream_t stream) {
    const float* s_in = (const float*)d_in[0];
    const float* W1   = (const float*)d_in[1];
    const float* W2   = (const float*)d_in[2];
    const float* Wf1  = (const float*)d_in[3];
    const float* Wf2  = (const float*)d_in[4];
    float* out = (float*)d_out;

    const size_t OFF_Z  = 0;               // max 157,286,400 (conv1 z planes)
    const size_t OFF_S0 = 157286400;       // u32 planes,  4,915,200
    const size_t OFF_S1 = 162201600;       // u32 planes, 39,321,600
    const size_t OFF_S2 = 201523200;       // u32 planes,  9,830,400
    const size_t OFF_S3 = 211353600;       // u32 planes, 19,660,800
    const size_t OFF_SB = 231014400;       // bf16 frag [8][20][64][512] = 10,485,760
    const size_t OFF_S5 = 241500160;       // f32 t-major, 4,915,200
    const size_t OFF_WF = 246415360;       // bf16 frag [3][32][64][512] = 6,291,456
    const size_t NEEDED = 252706816;

    if (ws_size < NEEDED) {
        k_zero<<<(26400 + 255) / 256, 256, 0, stream>>>(out, 26400);
        return;
    }

    char* ws = (char*)d_ws;
    float*    Z   = (float*)(ws + OFF_Z);
    uint32_t* s0p = (uint32_t*)(ws + OFF_S0);
    uint32_t* s1p = (uint32_t*)(ws + OFF_S1);
    uint32_t* s2p = (uint32_t*)(ws + OFF_S2);
    uint32_t* s3p = (uint32_t*)(ws + OFF_S3);
    ushort*   sbf = (ushort*)(ws + OFF_SB);
    float*    s5  = (float*)(ws + OFF_S5);
    ushort*   Wfr = (ushort*)(ws + OFF_WF);

    // Wf1 split into fragment-ordered bf16 planes
    k_wfrag<<<4096, 256, 0, stream>>>(Wf1, Wfr);

    // SP0: pool4 (t-major z) + scan -> u32 planes
    k_pool4<<<4800, 256, 0, stream>>>(s_in, Z);
    k_scan_l0<<<64, 256, 0, stream>>>(Z, s0p, 16384);

    // SC1: conv 5x5 (2->16), all-o-in-regs -> z planes; scan -> s1p
    k_conv1<<<2400, 256, 0, stream>>>(s0p, W1, (float4*)Z);
    k_scan_plane<<<512, 256, 0, stream>>>((const float4*)Z, s1p, 131072);

    // SP1: fused pool2+scan (32x32 -> 16x16, 128 bc)
    k_pool2s<16, 131072, 32768><<<128, 256, 0, stream>>>(s1p, s2p);

    // SC2: conv 3x3 (16->32), 16-o halves -> z planes; scan -> s3p
    k_conv2<<<1200, 256, 0, stream>>>(s2p, W2, (float4*)Z);
    k_scan_plane<<<256, 256, 0, stream>>>((const float4*)Z, s3p, 65536);

    // SP2: fused pool2+scan -> B-fragment bf16 spikes
    k_pool2s_bf<<<64, 256, 0, stream>>>(s3p, sbf);

    // SF1: fragment-layout MFMA GEMM -> t-major z; scan -> s5
    k_fc1_frag<<<640, 256, 0, stream>>>(Wfr, sbf, Z);
    k_scan_f32<<<16, 256, 0, stream>>>(Z, s5, 4096, 300);

    // SF2: FC 512->11 + final scan into d_out
    k_fc2<<<26, 256, 0, stream>>>(s5, Wf2, Z);
    k_scan_f32<<<1, 128, 0, stream>>>(Z, out, 88, 300);
}

// Round 10
// 865.111 us; speedup vs baseline: 4.8951x; 1.0276x over previous
//
#include <hip/hip_runtime.h>
#include <stdint.h>

#define T_STEPS 300
#define T4 75

typedef __attribute__((ext_vector_type(8))) short bf16x8;
typedef __attribute__((ext_vector_type(4))) float f32x4;

// ---- scan (psp + spike) constants: d = exp(-1), c = e, cr = -2*theta*e ----
__device__ __forceinline__ void scan_step(float x, float& pp, float& pq,
                                          float& rp, float& rq, float& s_out) {
    const float D  = 0.36787944117144233f;
    const float C  = 2.7182818284590452f;
    const float CR = -54.365636569180904f;
    const float TH = 10.0f;
    pq = D * (pq + pp);      // psp state (q uses old p)
    pp = D * pp + x;
    float u = C * pq;
    rq = D * (rq + rp);      // refractory state
    float s = (u + CR * rq >= TH) ? 1.0f : 0.0f;
    rp = D * rp + s;
    s_out = s;
}

#define SCAN4(v, PACK)                                                     \
    {                                                                      \
        float s0, s1, s2, s3;                                              \
        scan_step(v.x, pp, pq, rp, rq, s0);                                \
        scan_step(v.y, pp, pq, rp, rq, s1);                                \
        scan_step(v.z, pp, pq, rp, rq, s2);                                \
        scan_step(v.w, pp, pq, rp, rq, s3);                                \
        PACK = (uint32_t)s0 | ((uint32_t)s1 << 8) |                        \
               ((uint32_t)s2 << 16) | ((uint32_t)s3 << 24);                \
    }

#define FMA4(A, wc) A.x = fmaf(wc, f0, A.x); A.y = fmaf(wc, f1, A.y); \
                    A.z = fmaf(wc, f2, A.z); A.w = fmaf(wc, f3, A.w);

// ---- SP0 spatial: 4x4 sum-pool * 11 on raw input (t-major z out) ----
__global__ __launch_bounds__(256) void k_pool4(const float* __restrict__ in,
                                               float* __restrict__ z) {
    int idx = blockIdx.x * 256 + threadIdx.x;   // 16384 * 75
    int t4 = idx % T4;
    int n  = idx / T4;                // (b*2+c)*1024 + y*32 + x
    int x = n & 31, y = (n >> 5) & 31, bc = n >> 10;
    const float* base = in + ((size_t)bc * 16384 + (size_t)(4 * y) * 128 + 4 * x) * T_STEPS + 4 * t4;
    float4 acc = {0.f, 0.f, 0.f, 0.f};
#pragma unroll
    for (int i = 0; i < 4; ++i)
#pragma unroll
        for (int j = 0; j < 4; ++j) {
            float4 v = *reinterpret_cast<const float4*>(base + ((size_t)i * 128 + j) * T_STEPS);
            acc.x += v.x; acc.y += v.y; acc.z += v.z; acc.w += v.w;
        }
    float4 o = {11.f * acc.x, 11.f * acc.y, 11.f * acc.z, 11.f * acc.w};
    *reinterpret_cast<float4*>(z + (size_t)n * T_STEPS + 4 * t4) = o;
}

// ---- scan: t-major f32 z in -> u32 spike planes out (1-wave blocks) ----
__global__ __launch_bounds__(64) void k_scan_l0(const float* __restrict__ z,
                                                uint32_t* __restrict__ sp, int N) {
    int n = blockIdx.x * 64 + threadIdx.x;
    if (n >= N) return;
    const float4* zp = reinterpret_cast<const float4*>(z + (size_t)n * T_STEPS);
    float pp = 0.f, pq = 0.f, rp = 0.f, rq = 0.f;
#pragma unroll 2
    for (int t4 = 0; t4 < T4; ++t4) {
        float4 v = zp[t4];
        uint32_t pack;
        SCAN4(v, pack);
        sp[(size_t)t4 * N + n] = pack;
    }
}

// ---- scan: f4 z planes in -> u32 spike planes out ----
__global__ __launch_bounds__(256) void k_scan_plane(const float4* __restrict__ z,
                                                    uint32_t* __restrict__ sp, int N) {
    int n = blockIdx.x * 256 + threadIdx.x;
    if (n >= N) return;
    float pp = 0.f, pq = 0.f, rp = 0.f, rq = 0.f;
#pragma unroll 2
    for (int t4 = 0; t4 < T4; ++t4) {
        float4 v = z[(size_t)t4 * N + n];
        uint32_t pack;
        SCAN4(v, pack);
        sp[(size_t)t4 * N + n] = pack;
    }
}

// ---- scan: t-major f32 z in -> t-major f32 spikes out (FC tail, 1-wave blocks) ----
__global__ __launch_bounds__(64) void k_scan_f32(const float* __restrict__ z,
                                                 float* __restrict__ s, int N, int ostride) {
    int n = blockIdx.x * blockDim.x + threadIdx.x;
    if (n >= N) return;
    const float4* zp = reinterpret_cast<const float4*>(z + (size_t)n * T_STEPS);
    float* spo = s + (size_t)n * ostride;
    float pp = 0.f, pq = 0.f, rp = 0.f, rq = 0.f;
    for (int it = 0; it < T4; ++it) {
        float4 v = zp[it];
        float4 o;
        scan_step(v.x, pp, pq, rp, rq, o.x);
        scan_step(v.y, pp, pq, rp, rq, o.y);
        scan_step(v.z, pp, pq, rp, rq, o.z);
        scan_step(v.w, pp, pq, rp, rq, o.w);
        *reinterpret_cast<float4*>(spo + it * 4) = o;
    }
}

// ---- fused 2x2 sum-pool * 11 + scan on u32 spike planes (SP1, 1-wave blocks) ----
template<int HW, int NIN, int NOUT>
__global__ __launch_bounds__(64) void k_pool2s(const uint32_t* __restrict__ sin,
                                               uint32_t* __restrict__ sout) {
    int n = blockIdx.x * 64 + threadIdx.x;
    if (n >= NOUT) return;
    int x = n % HW, y = (n / HW) % HW, bc = n / (HW * HW);
    const int W2d = HW * 2;
    const uint32_t* base0 = sin + (size_t)bc * W2d * W2d + (size_t)(2 * y) * W2d + 2 * x;
    float pp = 0.f, pq = 0.f, rp = 0.f, rq = 0.f;
#pragma unroll 2
    for (int t4 = 0; t4 < T4; ++t4) {
        const uint32_t* p = base0 + (size_t)t4 * NIN;
        uint32_t sum = p[0] + p[1] + p[W2d] + p[W2d + 1];  // SWAR, bytes <= 4
        float4 v;
        v.x = 11.f * (float)(sum & 0xffu);
        v.y = 11.f * (float)((sum >> 8) & 0xffu);
        v.z = 11.f * (float)((sum >> 16) & 0xffu);
        v.w = 11.f * (float)(sum >> 24);
        uint32_t pack;
        SCAN4(v, pack);
        sout[(size_t)t4 * NOUT + n] = pack;
    }
}

// ---- SP2: fused 2x2 pool + scan -> spikes in B-FRAGMENT layout (1-wave blocks) ----
// sf[b][T=t>>4][ks=k>>5][lane][8] with lane = ((k>>3)&3)*16 + (t&15), elem j = k&7.
__global__ __launch_bounds__(64) void k_pool2s_bf(const uint32_t* __restrict__ sin,
                                                  ushort* __restrict__ sf) {
    int n = blockIdx.x * 64 + threadIdx.x;    // 16384 = b*2048 + k (k = c*64+y*8+x)
    if (n >= 16384) return;
    int x = n & 7, y = (n >> 3) & 7, bc = n >> 6;
    const uint32_t* base0 = sin + (size_t)bc * 256 + (size_t)(2 * y) * 16 + 2 * x;
    int b = n >> 11, k = n & 2047;
    size_t kpart = ((size_t)(k >> 5)) * 512 + (size_t)((k >> 3) & 3) * 128 + (k & 7);
    ushort* outb = sf + (size_t)b * 20 * 64 * 512 + kpart;
    float pp = 0.f, pq = 0.f, rp = 0.f, rq = 0.f;
    for (int t4 = 0; t4 < T4; ++t4) {
        const uint32_t* p = base0 + (size_t)t4 * 65536;
        uint32_t sum = p[0] + p[1] + p[16] + p[17];
        float4 v;
        v.x = 11.f * (float)(sum & 0xffu);
        v.y = 11.f * (float)((sum >> 8) & 0xffu);
        v.z = 11.f * (float)((sum >> 16) & 0xffu);
        v.w = 11.f * (float)(sum >> 24);
        float s0, s1, s2, s3;
        scan_step(v.x, pp, pq, rp, rq, s0);
        scan_step(v.y, pp, pq, rp, rq, s1);
        scan_step(v.z, pp, pq, rp, rq, s2);
        scan_step(v.w, pp, pq, rp, rq, s3);
        float sv[4] = {s0, s1, s2, s3};
#pragma unroll
        for (int r = 0; r < 4; ++r) {
            int t = t4 * 4 + r;
            outb[((size_t)(t >> 4) * 64) * 512 + (size_t)(t & 15) * 8] =
                sv[r] != 0.f ? (ushort)0x3F80 : (ushort)0;
        }
    }
}

// ---- SC1: 5x5 conv 2->16 over 32x32; thread = (b,pix,t4), ALL 16 o in regs ----
__global__ __launch_bounds__(256) void k_conv1(const uint32_t* __restrict__ s0p,
                                               const float* __restrict__ W1,
                                               float4* __restrict__ z1p) {
    __shared__ float w_lds[2][25][16];
    int bid = blockIdx.x;               // 2400
    int pixblk = bid & 3;
    int t4 = (bid >> 2) % 75;
    int b  = bid / 300;
    int tid = threadIdx.x;
    for (int j = tid; j < 800; j += 256) {
        int o = j & 15, kk = (j >> 4) % 25, c = j / 400;
        w_lds[c][kk][o] = W1[(o * 2 + c) * 25 + kk];
    }
    __syncthreads();
    int pix = pixblk * 256 + tid;
    int px = pix & 31, py = pix >> 5;
    float4 acc[16];
#pragma unroll
    for (int o = 0; o < 16; ++o) acc[o] = make_float4(0.f, 0.f, 0.f, 0.f);
    const uint32_t* pb = s0p + (size_t)t4 * 16384 + (size_t)(b * 2) * 1024;
    for (int c = 0; c < 2; ++c) {
#pragma unroll
        for (int ky = 0; ky < 5; ++ky) {
            int yy = py + ky - 2;
            bool rok = (unsigned)yy < 32u;
#pragma unroll
            for (int kx = 0; kx < 5; ++kx) {
                int xx = px + kx - 2;
                uint32_t v = 0;
                if (rok && (unsigned)xx < 32u) v = pb[c * 1024 + yy * 32 + xx];
                float f0 = (float)(v & 0xffu), f1 = (float)((v >> 8) & 0xffu);
                float f2 = (float)((v >> 16) & 0xffu), f3 = (float)(v >> 24);
                int kk = ky * 5 + kx;
#pragma unroll
                for (int oo = 0; oo < 4; ++oo) {
                    float4 w4 = *reinterpret_cast<const float4*>(&w_lds[c][kk][oo * 4]);
                    FMA4(acc[oo * 4 + 0], w4.x);
                    FMA4(acc[oo * 4 + 1], w4.y);
                    FMA4(acc[oo * 4 + 2], w4.z);
                    FMA4(acc[oo * 4 + 3], w4.w);
                }
            }
        }
    }
    size_t zb = (size_t)t4 * 131072 + (size_t)(b * 16) * 1024 + pix;
#pragma unroll
    for (int o = 0; o < 16; ++o) z1p[zb + o * 1024] = acc[o];
}

// ---- SC2: 3x3 conv 16->32 over 16x16; thread = (b,pix,t4), 16 o per half ----
__global__ __launch_bounds__(256) void k_conv2(const uint32_t* __restrict__ s2p,
                                               const float* __restrict__ W2,
                                               float4* __restrict__ z2p) {
    __shared__ float w_lds[16][9][16];
    int bid = blockIdx.x;               // 1200
    int oh = bid & 1;
    int t4 = (bid >> 1) % 75;
    int b  = bid / 150;
    int tid = threadIdx.x;              // pix (16x16)
    for (int j = tid; j < 2304; j += 256) {
        int o = j & 15;
        int t9 = (j >> 4) % 9;
        int c  = j / 144;
        w_lds[c][t9][o] = W2[(size_t)((oh * 16 + o) * 16 + c) * 9 + t9];
    }
    __syncthreads();
    int px = tid & 15, py = tid >> 4;
    float4 acc[16];
#pragma unroll
    for (int o = 0; o < 16; ++o) acc[o] = make_float4(0.f, 0.f, 0.f, 0.f);
    const uint32_t* pb = s2p + (size_t)t4 * 32768 + (size_t)(b * 16) * 256;
    for (int c = 0; c < 16; ++c) {
#pragma unroll
        for (int ky = 0; ky < 3; ++ky) {
            int yy = py + ky - 1;
            bool rok = (unsigned)yy < 16u;
#pragma unroll
            for (int kx = 0; kx < 3; ++kx) {
                int xx = px + kx - 1;
                uint32_t v = 0;
                if (rok && (unsigned)xx < 16u) v = pb[c * 256 + yy * 16 + xx];
                float f0 = (float)(v & 0xffu), f1 = (float)((v >> 8) & 0xffu);
                float f2 = (float)((v >> 16) & 0xffu), f3 = (float)(v >> 24);
                int t9 = ky * 3 + kx;
#pragma unroll
                for (int oo = 0; oo < 4; ++oo) {
                    float4 w4 = *reinterpret_cast<const float4*>(&w_lds[c][t9][oo * 4]);
                    FMA4(acc[oo * 4 + 0], w4.x);
                    FMA4(acc[oo * 4 + 1], w4.y);
                    FMA4(acc[oo * 4 + 2], w4.z);
                    FMA4(acc[oo * 4 + 3], w4.w);
                }
            }
        }
    }
    size_t zb = (size_t)t4 * 65536 + (size_t)(b * 32 + oh * 16) * 256 + tid;
#pragma unroll
    for (int o = 0; o < 16; ++o) z2p[zb + o * 256] = acc[o];
}

// ---- Wf1: 3-way bf16 split + A-FRAGMENT layout ----
__device__ __forceinline__ ushort f2bf(float f) {
    uint32_t u = __float_as_uint(f);
    u = u + 0x7fffu + ((u >> 16) & 1u);   // round-to-nearest-even
    return (ushort)(u >> 16);
}
__device__ __forceinline__ float bf2f(ushort h) {
    return __uint_as_float((uint32_t)h << 16);
}
__global__ __launch_bounds__(256) void k_wfrag(const float* __restrict__ W,
                                               ushort* __restrict__ Wf) {
    int i = blockIdx.x * 256 + threadIdx.x;   // 512*2048
    int o = i >> 11, k = i & 2047;
    float w = W[i];
    ushort h = f2bf(w);
    float r1 = w - bf2f(h);
    ushort m = f2bf(r1);
    float r2 = r1 - bf2f(m);
    ushort l = f2bf(r2);
    int lane = (((k >> 3) & 3) << 4) | (o & 15);
    size_t base = (((size_t)(o >> 4)) * 64 + (k >> 5)) * 512 + lane * 8 + (k & 7);
    const size_t PL = (size_t)32 * 64 * 512;
    Wf[base] = h;
    Wf[PL + base] = m;
    Wf[2 * PL + base] = l;
}

// ---- SF1: fragment-layout bf16 MFMA GEMM. No LDS, no barriers. ----
__device__ __forceinline__ bf16x8 ldb(const ushort* p) {
    return *reinterpret_cast<const bf16x8*>(p);
}
__global__ __launch_bounds__(256) void k_fc1_frag(const ushort* __restrict__ Wf,
                                                  const ushort* __restrict__ sf,
                                                  float* __restrict__ z) {
    int wv = threadIdx.x >> 6, lane = threadIdx.x & 63;
    int gw = blockIdx.x * 4 + wv;          // 0..2559
    int R  = gw & 31;
    int combo = gw >> 5;                   // 0..79
    int tp = combo % 10, b = combo / 10;
    int l15 = lane & 15, l4 = lane >> 4;

    const size_t PL = (size_t)32 * 64 * 512;
    const ushort* A0p = Wf + ((size_t)R * 64) * 512 + lane * 8;
    const ushort* A1p = A0p + PL;
    const ushort* A2p = A0p + 2 * PL;
    const ushort* B0p = sf + ((size_t)(b * 20 + 2 * tp + 0) * 64) * 512 + lane * 8;
    const ushort* B1p = B0p + (size_t)64 * 512;

    f32x4 acc0 = {0.f, 0.f, 0.f, 0.f};
    f32x4 acc1 = {0.f, 0.f, 0.f, 0.f};

    bf16x8 a0 = ldb(A0p), a1 = ldb(A1p), a2 = ldb(A2p);
    bf16x8 b0 = ldb(B0p), b1 = ldb(B1p);

    for (int ks = 0; ks < 64; ++ks) {
        int kn = (ks < 63) ? (ks + 1) * 512 : 0;   // last prefetch redundant
        bf16x8 na0 = ldb(A0p + kn), na1 = ldb(A1p + kn), na2 = ldb(A2p + kn);
        bf16x8 nb0 = ldb(B0p + kn), nb1 = ldb(B1p + kn);
        acc0 = __builtin_amdgcn_mfma_f32_16x16x32_bf16(a0, b0, acc0, 0, 0, 0);
        acc1 = __builtin_amdgcn_mfma_f32_16x16x32_bf16(a0, b1, acc1, 0, 0, 0);
        acc0 = __builtin_amdgcn_mfma_f32_16x16x32_bf16(a1, b0, acc0, 0, 0, 0);
        acc1 = __builtin_amdgcn_mfma_f32_16x16x32_bf16(a1, b1, acc1, 0, 0, 0);
        acc0 = __builtin_amdgcn_mfma_f32_16x16x32_bf16(a2, b0, acc0, 0, 0, 0);
        acc1 = __builtin_amdgcn_mfma_f32_16x16x32_bf16(a2, b1, acc1, 0, 0, 0);
        a0 = na0; a1 = na1; a2 = na2; b0 = nb0; b1 = nb1;
    }

    int orow = R * 16 + l4 * 4;
    int tb = tp * 32;
    {
        int tc = tb + l15;
        if (tc < T_STEPS) {
            float* zr = z + ((size_t)b * 512 + orow) * T_STEPS + tc;
            zr[0 * T_STEPS] = acc0.x; zr[1 * T_STEPS] = acc0.y;
            zr[2 * T_STEPS] = acc0.z; zr[3 * T_STEPS] = acc0.w;
        }
    }
    {
        int tc = tb + 16 + l15;
        if (tc < T_STEPS) {
            float* zr = z + ((size_t)b * 512 + orow) * T_STEPS + tc;
            zr[0 * T_STEPS] = acc1.x; zr[1 * T_STEPS] = acc1.y;
            zr[2 * T_STEPS] = acc1.z; zr[3 * T_STEPS] = acc1.w;
        }
    }
}

// ---- SF2: 512 -> 11 FC (t-major f32 spikes, 1-wave blocks) ----
__global__ __launch_bounds__(64) void k_fc2(const float* __restrict__ s5,
                                            const float* __restrict__ Wf2,
                                            float* __restrict__ z) {
    int idx = blockIdx.x * 64 + threadIdx.x;    // 11*8*75 = 6600
    if (idx >= 6600) return;
    int t4 = idx % T4;
    int r  = idx / T4;            // o*8 + b
    int b = r & 7, o = r >> 3;
    const float* sp = s5 + (size_t)b * 512 * T_STEPS + 4 * t4;
    const float* wp = Wf2 + (size_t)o * 512;
    float a0 = 0.f, a1 = 0.f, a2 = 0.f, a3 = 0.f;
#pragma unroll 2
    for (int k = 0; k < 512; k += 4) {
        float4 wv = *reinterpret_cast<const float4*>(wp + k);
        float4 v0 = *reinterpret_cast<const float4*>(sp + (size_t)(k + 0) * T_STEPS);
        float4 v1 = *reinterpret_cast<const float4*>(sp + (size_t)(k + 1) * T_STEPS);
        float4 v2 = *reinterpret_cast<const float4*>(sp + (size_t)(k + 2) * T_STEPS);
        float4 v3 = *reinterpret_cast<const float4*>(sp + (size_t)(k + 3) * T_STEPS);
        a0 = fmaf(wv.x, v0.x, a0); a1 = fmaf(wv.x, v0.y, a1); a2 = fmaf(wv.x, v0.z, a2); a3 = fmaf(wv.x, v0.w, a3);
        a0 = fmaf(wv.y, v1.x, a0); a1 = fmaf(wv.y, v1.y, a1); a2 = fmaf(wv.y, v1.z, a2); a3 = fmaf(wv.y, v1.w, a3);
        a0 = fmaf(wv.z, v2.x, a0); a1 = fmaf(wv.z, v2.y, a1); a2 = fmaf(wv.z, v2.z, a2); a3 = fmaf(wv.z, v2.w, a3);
        a0 = fmaf(wv.w, v3.x, a0); a1 = fmaf(wv.w, v3.y, a1); a2 = fmaf(wv.w, v3.z, a2); a3 = fmaf(wv.w, v3.w, a3);
    }
    *reinterpret_cast<float4*>(z + (size_t)(b * 11 + o) * T_STEPS + 4 * t4) = make_float4(a0, a1, a2, a3);
}

__global__ void k_zero(float* out, int n) {
    int i = blockIdx.x * 256 + threadIdx.x;
    if (i < n) out[i] = 0.f;
}

extern "C" void kernel_launch(void* const* d_in, const int* in_sizes, int n_in,
                              void* d_out, int out_size, void* d_ws, size_t ws_size,
                              hipStream_t stream) {
    const float* s_in = (const float*)d_in[0];
    const float* W1   = (const float*)d_in[1];
    const float* W2   = (const float*)d_in[2];
    const float* Wf1  = (const float*)d_in[3];
    const float* Wf2  = (const float*)d_in[4];
    float* out = (float*)d_out;

    const size_t OFF_Z  = 0;               // max 157,286,400 (conv1 z planes)
    const size_t OFF_S0 = 157286400;       // u32 planes,  4,915,200
    const size_t OFF_S1 = 162201600;       // u32 planes, 39,321,600
    const size_t OFF_S2 = 201523200;       // u32 planes,  9,830,400
    const size_t OFF_S3 = 211353600;       // u32 planes, 19,660,800
    const size_t OFF_SB = 231014400;       // bf16 frag [8][20][64][512] = 10,485,760
    const size_t OFF_S5 = 241500160;       // f32 t-major, 4,915,200
    const size_t OFF_WF = 246415360;       // bf16 frag [3][32][64][512] = 6,291,456
    const size_t NEEDED = 252706816;

    if (ws_size < NEEDED) {
        k_zero<<<(26400 + 255) / 256, 256, 0, stream>>>(out, 26400);
        return;
    }

    char* ws = (char*)d_ws;
    float*    Z   = (float*)(ws + OFF_Z);
    uint32_t* s0p = (uint32_t*)(ws + OFF_S0);
    uint32_t* s1p = (uint32_t*)(ws + OFF_S1);
    uint32_t* s2p = (uint32_t*)(ws + OFF_S2);
    uint32_t* s3p = (uint32_t*)(ws + OFF_S3);
    ushort*   sbf = (ushort*)(ws + OFF_SB);
    float*    s5  = (float*)(ws + OFF_S5);
    ushort*   Wfr = (ushort*)(ws + OFF_WF);

    // Wf1 split into fragment-ordered bf16 planes
    k_wfrag<<<4096, 256, 0, stream>>>(Wf1, Wfr);

    // SP0: pool4 (t-major z) + scan -> u32 planes
    k_pool4<<<4800, 256, 0, stream>>>(s_in, Z);
    k_scan_l0<<<256, 64, 0, stream>>>(Z, s0p, 16384);

    // SC1: conv 5x5 (2->16), all-o-in-regs -> z planes; scan -> s1p
    k_conv1<<<2400, 256, 0, stream>>>(s0p, W1, (float4*)Z);
    k_scan_plane<<<512, 256, 0, stream>>>((const float4*)Z, s1p, 131072);

    // SP1: fused pool2+scan (32x32 -> 16x16), 1-wave blocks across all CUs
    k_pool2s<16, 131072, 32768><<<512, 64, 0, stream>>>(s1p, s2p);

    // SC2: conv 3x3 (16->32), 16-o halves -> z planes; scan -> s3p
    k_conv2<<<1200, 256, 0, stream>>>(s2p, W2, (float4*)Z);
    k_scan_plane<<<256, 256, 0, stream>>>((const float4*)Z, s3p, 65536);

    // SP2: fused pool2+scan -> B-fragment bf16 spikes, 1-wave blocks
    k_pool2s_bf<<<256, 64, 0, stream>>>(s3p, sbf);

    // SF1: fragment-layout MFMA GEMM -> t-major z; scan -> s5 (1-wave blocks)
    k_fc1_frag<<<640, 256, 0, stream>>>(Wfr, sbf, Z);
    k_scan_f32<<<64, 64, 0, stream>>>(Z, s5, 4096, 300);

    // SF2: FC 512->11 (1-wave blocks) + final scan into d_out
    k_fc2<<<104, 64, 0, stream>>>(s5, Wf2, Z);
    k_scan_f32<<<2, 64, 0, stream>>>(Z, out, 88, 300);
}